// Round 6
// baseline (213.550 us; speedup 1.0000x reference)
//
#include <hip/hip_runtime.h>
#include <hip/hip_bf16.h>
#include <hip/hip_fp16.h>
#include <math.h>

#define B_   4
#define N_   4096
#define K_   16
#define DP_  128
#define DM_  256
#define NPTS (B_ * N_)
#define SEG_ 16
#define CAND_ (N_ / SEG_)   // 256 candidates per segment
#define QPAD 136            // K=128 LDS row stride (f16): 272B, uint4-aligned, low conflict

typedef unsigned int u32;
typedef unsigned char u8;
typedef _Float16 f16;
typedef __attribute__((ext_vector_type(2))) __fp16 h2;     // matches cvt_pkrtz ABI
typedef __attribute__((ext_vector_type(8))) _Float16 f16x8; // MFMA operand
typedef __attribute__((ext_vector_type(4))) float floatx4;

static __device__ __forceinline__ h2 pkrtz(float a, float b) {
    return __builtin_amdgcn_cvt_pkrtz(a, b);
}
static __device__ __forceinline__ u32 asu32(h2 h) { return __builtin_bit_cast(u32, h); }
static __device__ __forceinline__ h2 ash2(u32 u) { return __builtin_bit_cast(h2, u); }

// ---- bitonic primitives on u32 registers ----
#define CEXA(x, y) { u32 _lo = min(x, y); y = max(x, y); x = _lo; }   // x<=y
#define CEXD(x, y) { u32 _hi = max(x, y); y = min(x, y); x = _hi; }   // x>=y

// Batcher odd-even mergesort network, 16 elements, 63 comparators (vs 80 for
// bitonic), depth 10. All comparators CEXD -> fully sorted DESCENDING.
static __device__ __forceinline__ void sort16_desc(u32 c[16]) {
    // L1
    CEXD(c[0],c[1]);  CEXD(c[2],c[3]);  CEXD(c[4],c[5]);  CEXD(c[6],c[7]);
    CEXD(c[8],c[9]);  CEXD(c[10],c[11]); CEXD(c[12],c[13]); CEXD(c[14],c[15]);
    // L2
    CEXD(c[0],c[2]);  CEXD(c[1],c[3]);  CEXD(c[4],c[6]);  CEXD(c[5],c[7]);
    CEXD(c[8],c[10]); CEXD(c[9],c[11]); CEXD(c[12],c[14]); CEXD(c[13],c[15]);
    // L3
    CEXD(c[1],c[2]);  CEXD(c[5],c[6]);  CEXD(c[9],c[10]); CEXD(c[13],c[14]);
    // L4
    CEXD(c[0],c[4]);  CEXD(c[1],c[5]);  CEXD(c[2],c[6]);  CEXD(c[3],c[7]);
    CEXD(c[8],c[12]); CEXD(c[9],c[13]); CEXD(c[10],c[14]); CEXD(c[11],c[15]);
    // L5
    CEXD(c[2],c[4]);  CEXD(c[3],c[5]);  CEXD(c[10],c[12]); CEXD(c[11],c[13]);
    // L6
    CEXD(c[1],c[2]);  CEXD(c[3],c[4]);  CEXD(c[5],c[6]);
    CEXD(c[9],c[10]); CEXD(c[11],c[12]); CEXD(c[13],c[14]);
    // L7 (merge 8+8)
    CEXD(c[0],c[8]);  CEXD(c[1],c[9]);  CEXD(c[2],c[10]); CEXD(c[3],c[11]);
    CEXD(c[4],c[12]); CEXD(c[5],c[13]); CEXD(c[6],c[14]); CEXD(c[7],c[15]);
    // L8
    CEXD(c[4],c[8]);  CEXD(c[5],c[9]);  CEXD(c[6],c[10]); CEXD(c[7],c[11]);
    // L9
    CEXD(c[2],c[4]);  CEXD(c[3],c[5]);  CEXD(c[6],c[8]);  CEXD(c[7],c[9]);
    CEXD(c[10],c[12]); CEXD(c[11],c[13]);
    // L10
    CEXD(c[1],c[2]);  CEXD(c[3],c[4]);  CEXD(c[5],c[6]);  CEXD(c[7],c[8]);
    CEXD(c[9],c[10]); CEXD(c[11],c[12]); CEXD(c[13],c[14]);
}

static __device__ __forceinline__ void remerge16_asc(u32 L[16]) {
    CEXA(L[0],L[8]);  CEXA(L[1],L[9]);  CEXA(L[2],L[10]); CEXA(L[3],L[11]);
    CEXA(L[4],L[12]); CEXA(L[5],L[13]); CEXA(L[6],L[14]); CEXA(L[7],L[15]);
    CEXA(L[0],L[4]);  CEXA(L[1],L[5]);  CEXA(L[2],L[6]);  CEXA(L[3],L[7]);
    CEXA(L[8],L[12]); CEXA(L[9],L[13]); CEXA(L[10],L[14]); CEXA(L[11],L[15]);
    CEXA(L[0],L[2]);  CEXA(L[1],L[3]);  CEXA(L[4],L[6]);  CEXA(L[5],L[7]);
    CEXA(L[8],L[10]); CEXA(L[9],L[11]); CEXA(L[12],L[14]); CEXA(L[13],L[15]);
    CEXA(L[0],L[1]);  CEXA(L[2],L[3]);  CEXA(L[4],L[5]);  CEXA(L[6],L[7]);
    CEXA(L[8],L[9]);  CEXA(L[10],L[11]); CEXA(L[12],L[13]); CEXA(L[14],L[15]);
}

// ---------------- KNN part body (R1 variant — best measured, 43.5 µs) ----------------
static __device__ void knn_part_body(float4* sc, const float* __restrict__ xyz,
                                     u32* __restrict__ part, int id)
{
    const int xblk = id & 15;            // N_/256 = 16
    const int s = (id >> 4) & 15;        // SEG_ = 16
    const int b = id >> 8;               // B_ = 4
    const int n = xblk * 256 + threadIdx.x;
    const float* xb = xyz + (size_t)b * N_ * 3;
    const float x0 = xb[n * 3 + 0], x1 = xb[n * 3 + 1], x2 = xb[n * 3 + 2];
    const float nx0 = -x0, nx1 = -x1, nx2 = -x2;
    // e = 0.5*|y|^2 - x.y + 0.5*|x|^2 = 0.5*d^2 >= 0 (up to rounding) -> raw
    // positive-float bits are a monotone sort key; fmax clamp protects the
    // self-point (rounding could make its e tiny-negative -> huge u32 key).
    const float hs = 0.5f * fmaf(x0, x0, fmaf(x1, x1, x2 * x2));
    const u32 kmask = 0xFFFFF000u;

    {
        const int m = s * CAND_ + threadIdx.x;   // CAND_ == 256 == blockDim.x
        const float a0 = xb[m * 3 + 0];
        const float a1 = xb[m * 3 + 1];
        const float a2 = xb[m * 3 + 2];
        sc[threadIdx.x] = make_float4(a0, a1, a2, 0.5f * (a0 * a0 + a1 * a1 + a2 * a2));
    }
    __syncthreads();

    u32 L[16];
#pragma unroll
    for (int i = 0; i < 16; ++i) L[i] = 0xFFFFFFFFu;

    const u32 ibase = (u32)(s * CAND_);
    for (int m0 = 0; m0 < CAND_; m0 += 16) {
        float4 cc[16];
#pragma unroll
        for (int t = 0; t < 16; ++t) cc[t] = sc[m0 + t];
        u32 c[16];
#pragma unroll
        for (int t = 0; t < 16; ++t) {
            const float e = fmaf(nx0, cc[t].x,
                            fmaf(nx1, cc[t].y,
                            fmaf(nx2, cc[t].z, cc[t].w + hs)));
            c[t] = (__float_as_uint(fmaxf(e, 0.0f)) & kmask) | (ibase + (u32)(m0 + t));
        }
        sort16_desc(c);
#pragma unroll
        for (int i = 0; i < 16; ++i) L[i] = min(L[i], c[i]);
        remerge16_asc(L);
    }

    const int p = b * N_ + n;
#pragma unroll
    for (int j = 0; j < 16; ++j)
        part[(size_t)(s * 16 + j) * NPTS + p] = L[j];
}

// ---------------- prep body: weight transpose-casts + straight casts (f16) ----------------
static __device__ void prep_body(float (*t)[33],
    const float* __restrict__ wq, const float* __restrict__ wk, const float* __restrict__ wv,
    const float* __restrict__ fd2, const float* __restrict__ fc1, const float* __restrict__ fc2,
    const float* __restrict__ feat,
    f16* __restrict__ catW, f16* __restrict__ fc2T, f16* __restrict__ bt2,
    f16* __restrict__ fd2c, f16* __restrict__ wqc, f16* __restrict__ fc1c,
    f16* __restrict__ featb, int bx, int by, int job)
{
    const int tid = threadIdx.x;

    if (job < 4) {
        const float* in; int R, C;
        switch (job) {
            case 0: in = wq;  R = DM_; C = DM_; break;
            case 1: in = wk;  R = DM_; C = DM_; break;
            case 2: in = wv;  R = DM_; C = DM_; break;
            default: in = fc2; R = DM_; C = DP_; break;
        }
        const int c0 = bx * 32, r0 = by * 32;
        if (c0 >= C || r0 >= R) return;
        const int lx = tid & 31, ly = tid >> 5;
#pragma unroll
        for (int i = 0; i < 32; i += 8)
            t[ly + i][lx] = in[(size_t)(r0 + ly + i) * C + c0 + lx];
        __syncthreads();
#pragma unroll
        for (int i = 0; i < 32; i += 8) {
            const int c = c0 + ly + i;
            const f16 v = (f16)t[lx][ly + i];
            int n;
            switch (job) {
                case 0: n = c; break;
                case 1: n = 256 + ((c >> 2) << 3) + (c & 3); break;
                case 2: n = 256 + ((c >> 2) << 3) + 4 + (c & 3); break;
                default: n = -1; break;
            }
            if (job < 3) {
                catW[(size_t)n * DM_ + r0 + lx] = v;
            } else {
                fc2T[(size_t)c * DM_ + r0 + lx] = v;
                bt2[(size_t)c * 512 + 256 + r0 + lx] = v;
            }
        }
    } else {
        const int bid = by * 8 + bx;                      // 0..63
        const int tId = bid * 256 + tid;
        const float* in; f16* outp; int n4;
        if (job == 4)      { in = fd2;  outp = fd2c;  n4 = (DM_ * DM_) / 4; }
        else if (job == 5) { in = wq;   outp = wqc;   n4 = (DM_ * DM_) / 4; }
        else if (job == 6) { in = fc1;  outp = fc1c;  n4 = (DP_ * DM_) / 4; }
        else               { in = feat; outp = featb; n4 = (NPTS * DP_) / 4; }
        for (int i = tId; i < n4; i += 16384) {
            const float4 v = ((const float4*)in)[i];
            const u32 lo = asu32(pkrtz(v.x, v.y));
            const u32 hi = asu32(pkrtz(v.z, v.w));
            ((uint2*)outp)[i] = make_uint2(lo, hi);
        }
    }
}

// ---------------- FUSED prep (512 blocks) + knn_part (1024 blocks) ----------------
__global__ __launch_bounds__(256) void fused_prep_knn_kernel(
    const float* __restrict__ wq, const float* __restrict__ wk, const float* __restrict__ wv,
    const float* __restrict__ fd2, const float* __restrict__ fc1, const float* __restrict__ fc2,
    const float* __restrict__ feat,
    f16* __restrict__ catW, f16* __restrict__ fc2T, f16* __restrict__ bt2,
    f16* __restrict__ fd2c, f16* __restrict__ wqc, f16* __restrict__ fc1c,
    f16* __restrict__ featb,
    const float* __restrict__ xyz, u32* __restrict__ part)
{
    __shared__ __align__(16) char smem[4352];
    const int id = blockIdx.x;
    if (id < 512) {
        prep_body((float(*)[33])smem, wq, wk, wv, fd2, fc1, fc2, feat,
                  catW, fc2T, bt2, fd2c, wqc, fc1c, featb,
                  id & 7, (id >> 3) & 7, id >> 6);
    } else {
        knn_part_body((float4*)smem, xyz, part, id - 512);
    }
}

// ---------------- generic BK=32 GEMM tile (C[M,N] = A@Bt^T, f16 out) ----------------
static __device__ void gemm_tile(f16* As, f16* Bs,
    const f16* __restrict__ A, const f16* __restrict__ Bt,
    f16* __restrict__ Cb,
    int M, int N, int K, int ldc, int bx, int by)
{
    const int tid = threadIdx.x;
    const int m0 = by * 128, n0 = bx * 128;
    const int w = tid >> 6, l = tid & 63;
    const int wm = (w >> 1) * 64, wn = (w & 1) * 64;
    const int fm = l & 15, kq = l >> 4;

    floatx4 acc[4][4];
#pragma unroll
    for (int i = 0; i < 4; ++i)
#pragma unroll
        for (int j = 0; j < 4; ++j)
            acc[i][j] = (floatx4){0.0f, 0.0f, 0.0f, 0.0f};

    for (int k0 = 0; k0 < K; k0 += 32) {
        __syncthreads();
#pragma unroll
        for (int c = 0; c < 2; ++c) {
            const int li = tid + c * 256;
            const int row = li >> 2, part = li & 3;
            *(uint4*)&As[row * 32 + part * 8] =
                *(const uint4*)&A[(size_t)(m0 + row) * K + k0 + part * 8];
            *(uint4*)&Bs[row * 32 + part * 8] =
                *(const uint4*)&Bt[(size_t)(n0 + row) * K + k0 + part * 8];
        }
        __syncthreads();
        f16x8 af[4], bf[4];
#pragma unroll
        for (int i = 0; i < 4; ++i)
            af[i] = *(const f16x8*)&As[(wm + i * 16 + fm) * 32 + kq * 8];
#pragma unroll
        for (int j = 0; j < 4; ++j)
            bf[j] = *(const f16x8*)&Bs[(wn + j * 16 + fm) * 32 + kq * 8];
#pragma unroll
        for (int i = 0; i < 4; ++i)
#pragma unroll
            for (int j = 0; j < 4; ++j)
                acc[i][j] = __builtin_amdgcn_mfma_f32_16x16x32_f16(af[i], bf[j], acc[i][j], 0, 0, 0);
    }

#pragma unroll
    for (int i = 0; i < 4; ++i) {
#pragma unroll
        for (int j = 0; j < 4; ++j) {
            const int col = n0 + wn + j * 16 + fm;
            const int rowb = m0 + wm + i * 16 + kq * 4;
#pragma unroll
            for (int r = 0; r < 4; ++r)
                Cb[(size_t)(rowb + r) * ldc + col] = (f16)acc[i][j][r];
        }
    }
}

static __device__ void mergeAB_body(const u32* __restrict__ part, int* __restrict__ knn_idx,
                                    int id)
{
    const int p = id * 256 + threadIdx.x;
    const int b = p >> 12;

    u32 L[16];
#pragma unroll
    for (int i = 0; i < 16; ++i) L[i] = 0xFFFFFFFFu;

    for (int s = 0; s < SEG_; ++s) {
        u32 seg[16];
#pragma unroll
        for (int j = 0; j < 16; ++j)
            seg[j] = part[(size_t)(s * 16 + j) * NPTS + p];
#pragma unroll
        for (int i = 0; i < 16; ++i) L[i] = min(L[i], seg[15 - i]);
        remerge16_asc(L);
    }

    int* o = knn_idx + (size_t)p * K_;
#pragma unroll
    for (int i = 0; i < 16; ++i) o[i] = b * N_ + (int)(L[i] & 0xFFFu);
}

// ---------------- qkv GEMM, 64-row x 1024-col blocks, fused kvw/ubuf epilogue ----------
// Block computes all 1024 output cols for 64 rows (B streamed through LDS).
// kv n-tiles (cols 256..767) never touch HBM: staged f16 in LDS (same rounding
// as the old global round-trip), then packed to fp8 kvw rows + w/u vectors in
// the epilogue. q (cols 0..255) and qp (768..1023) written to qkv as before.
// Blocks 256.. run the 16-segment KNN merge (fused to save a launch).
#define KVP 520   // kvs row stride (f16): 1040B -> bank offset 4 per row
__global__ __launch_bounds__(256) void gemm_qkv_fused_kernel(
    const f16* __restrict__ A,     // featb [NPTS][128]
    const f16* __restrict__ Bt,    // WallT [1024][128]
    const float* __restrict__ bias,
    const float* __restrict__ xyz,
    const float* __restrict__ fd1_w, const float* __restrict__ fd1_b,
    f16* __restrict__ Cb,          // qkv [NPTS][1024] (q/qp cols only)
    u8* __restrict__ kvw, f16* __restrict__ ubuf,
    const u32* __restrict__ part, int* __restrict__ knn_idx)
{
    __shared__ __align__(16) f16 As[64 * 136];
    __shared__ __align__(16) f16 Bs[128 * 136];
    __shared__ __align__(16) f16 kvs[64 * KVP];
    const int bid = blockIdx.x;
    if (bid >= 256) { mergeAB_body(part, knn_idx, bid - 256); return; }

    const int tid = threadIdx.x;
    const int m0 = bid * 64;
    const int w = tid >> 6, l = tid & 63;
    const int wr = (w >> 1) * 32;          // wave row offset within 64
    const int wn = (w & 1) * 64;           // wave col offset within 128-tile
    const int fm = l & 15, kq = l >> 4;

    // stage A rows m0..m0+63: 64 rows x 16 uint4-chunks = 1024 slots
#pragma unroll
    for (int c = 0; c < 4; ++c) {
        const int li = tid + c * 256;      // 0..1023
        const int row = li >> 4, pt = li & 15;
        *(uint4*)&As[row * 136 + pt * 8] =
            *(const uint4*)&A[(size_t)(m0 + row) * 128 + pt * 8];
    }

    for (int nt = 0; nt < 8; ++nt) {
        __syncthreads();   // As ready (iter 0) / prior Bs reads done
        // stage B rows nt*128..+127: 128 rows x 16 chunks = 2048 slots
#pragma unroll
        for (int c = 0; c < 8; ++c) {
            const int li = tid + c * 256;  // 0..2047
            const int row = li >> 4, pt = li & 15;
            *(uint4*)&Bs[row * 136 + pt * 8] =
                *(const uint4*)&Bt[(size_t)(nt * 128 + row) * 128 + pt * 8];
        }
        __syncthreads();

        floatx4 acc[2][4];
#pragma unroll
        for (int i = 0; i < 2; ++i)
#pragma unroll
            for (int j = 0; j < 4; ++j)
                acc[i][j] = (floatx4){0.0f, 0.0f, 0.0f, 0.0f};

#pragma unroll
        for (int kk = 0; kk < 4; ++kk) {
            f16x8 af[2], bf[4];
#pragma unroll
            for (int i = 0; i < 2; ++i)
                af[i] = *(const f16x8*)&As[(wr + i * 16 + fm) * 136 + kk * 32 + kq * 8];
#pragma unroll
            for (int j = 0; j < 4; ++j)
                bf[j] = *(const f16x8*)&Bs[(wn + j * 16 + fm) * 136 + kk * 32 + kq * 8];
#pragma unroll
            for (int i = 0; i < 2; ++i)
#pragma unroll
                for (int j = 0; j < 4; ++j)
                    acc[i][j] = __builtin_amdgcn_mfma_f32_16x16x32_f16(af[i], bf[j], acc[i][j], 0, 0, 0);
        }

        if (nt >= 2 && nt < 6) {
            // kv cols -> LDS (f16 round identical to old global round-trip)
#pragma unroll
            for (int i = 0; i < 2; ++i) {
#pragma unroll
                for (int j = 0; j < 4; ++j) {
                    const int col = nt * 128 + wn + j * 16 + fm;   // global col 256..767
                    const int lcol = col - 256;
                    const int rowb = wr + i * 16 + kq * 4;
#pragma unroll
                    for (int r = 0; r < 4; ++r)
                        kvs[(rowb + r) * KVP + lcol] = (f16)(acc[i][j][r] + bias[col]);
                }
            }
        } else {
#pragma unroll
            for (int i = 0; i < 2; ++i) {
#pragma unroll
                for (int j = 0; j < 4; ++j) {
                    const int col = nt * 128 + wn + j * 16 + fm;
                    const int rowb = m0 + wr + i * 16 + kq * 4;
#pragma unroll
                    for (int r = 0; r < 4; ++r)
                        Cb[(size_t)(rowb + r) * 1024 + col] = (f16)(acc[i][j][r] + bias[col]);
                }
            }
        }
    }
    __syncthreads();

    // epilogue: pack kvw rows {k fp8, v fp8, w f16} + ubuf (u = w + fd1_b).
    // 64 rows x 64 groups = 4096 tasks, 16 per thread; per-wave p is uniform.
    for (int it = 0; it < 16; ++it) {
        const int task = it * 256 + tid;
        const int pl = task >> 6, g = task & 63;
        const int p = m0 + pl;
        const uint4 kv = *(const uint4*)&kvs[pl * KVP + g * 8];
        const h2 k01 = ash2(kv.x), k23 = ash2(kv.y), v01 = ash2(kv.z), v23 = ash2(kv.w);
        int lo = 0, hi = 0;
        lo = __builtin_amdgcn_cvt_pk_fp8_f32((float)k01.x, (float)k01.y, lo, false);
        lo = __builtin_amdgcn_cvt_pk_fp8_f32((float)k23.x, (float)k23.y, lo, true);
        hi = __builtin_amdgcn_cvt_pk_fp8_f32((float)v01.x, (float)v01.y, hi, false);
        hi = __builtin_amdgcn_cvt_pk_fp8_f32((float)v23.x, (float)v23.y, hi, true);

        const float x0 = xyz[(size_t)p * 3 + 0];
        const float x1 = xyz[(size_t)p * 3 + 1];
        const float x2 = xyz[(size_t)p * 3 + 2];
        const int c0 = g * 4;
        const float4 w0v = *(const float4*)&fd1_w[c0];
        const float4 w1v = *(const float4*)&fd1_w[DM_ + c0];
        const float4 w2v = *(const float4*)&fd1_w[2 * DM_ + c0];
        const float4 b1v = *(const float4*)&fd1_b[c0];
        const float ww0 = x0 * w0v.x + x1 * w1v.x + x2 * w2v.x;
        const float ww1 = x0 * w0v.y + x1 * w1v.y + x2 * w2v.y;
        const float ww2 = x0 * w0v.z + x1 * w1v.z + x2 * w2v.z;
        const float ww3 = x0 * w0v.w + x1 * w1v.w + x2 * w2v.w;

        uint4 row;
        row.x = (u32)lo;
        row.y = (u32)hi;
        row.z = asu32(pkrtz(ww0, ww1));
        row.w = asu32(pkrtz(ww2, ww3));
        *(uint4*)(kvw + (size_t)p * 1024 + g * 16) = row;

        const uint2 uu = make_uint2(asu32(pkrtz(ww0 + b1v.x, ww1 + b1v.y)),
                                    asu32(pkrtz(ww2 + b1v.z, ww3 + b1v.w)));
        *(uint2*)(ubuf + (size_t)p * 256 + c0) = uu;
    }
}

// ---------------- out GEMM: 64x128 tile (256 blocks — full CU coverage) ----------------
__global__ __launch_bounds__(256) void gemm_out_kernel(
    const f16* __restrict__ A,      // ab [NPTS][512]
    const f16* __restrict__ Bt,     // bt2 [128][512]
    const float* __restrict__ bias2,
    const float* __restrict__ feat, // [NPTS][128] fp32
    float* __restrict__ CT)         // [B][DP][N]
{
    __shared__ __align__(16) f16 As[64 * 32];
    __shared__ __align__(16) f16 Bs[128 * 32];
    const int tid = threadIdx.x;
    const int m0 = blockIdx.x * 64;
    const int w = tid >> 6, l = tid & 63;
    const int wn = w * 32;
    const int fm = l & 15, kq = l >> 4;

    floatx4 acc[4][2];
#pragma unroll
    for (int i = 0; i < 4; ++i)
#pragma unroll
        for (int j = 0; j < 2; ++j)
            acc[i][j] = (floatx4){0.0f, 0.0f, 0.0f, 0.0f};

    for (int k0 = 0; k0 < 512; k0 += 32) {
        __syncthreads();
        {
            const int row = tid >> 2, part = tid & 3;
            *(uint4*)&As[row * 32 + part * 8] =
                *(const uint4*)&A[(size_t)(m0 + row) * 512 + k0 + part * 8];
        }
#pragma unroll
        for (int c = 0; c < 2; ++c) {
            const int li = tid + c * 256;
            const int row = li >> 2, part = li & 3;
            *(uint4*)&Bs[row * 32 + part * 8] =
                *(const uint4*)&Bt[(size_t)row * 512 + k0 + part * 8];
        }
        __syncthreads();
        f16x8 af[4], bf[2];
#pragma unroll
        for (int i = 0; i < 4; ++i)
            af[i] = *(const f16x8*)&As[(i * 16 + fm) * 32 + kq * 8];
#pragma unroll
        for (int j = 0; j < 2; ++j)
            bf[j] = *(const f16x8*)&Bs[(wn + j * 16 + fm) * 32 + kq * 8];
#pragma unroll
        for (int i = 0; i < 4; ++i)
#pragma unroll
            for (int j = 0; j < 2; ++j)
                acc[i][j] = __builtin_amdgcn_mfma_f32_16x16x32_f16(af[i], bf[j], acc[i][j], 0, 0, 0);
    }

#pragma unroll
    for (int i = 0; i < 4; ++i) {
#pragma unroll
        for (int j = 0; j < 2; ++j) {
            const int col = wn + j * 16 + fm;
            const int rowb = m0 + i * 16 + kq * 4;
            float4 vv;
#pragma unroll
            for (int r = 0; r < 4; ++r)
                ((float*)&vv)[r] = acc[i][j][r] + bias2[col]
                                 + feat[(size_t)(rowb + r) * DP_ + col];
            const int bb = rowb >> 12;
            *(float4*)&CT[(size_t)(bb * DP_ + col) * N_ + (rowb & (N_ - 1))] = vv;
        }
    }
}

// ---------------- fused small GEMMs 1: wqp (4 tiles) + bt2 (2 tiles) ----------------
__global__ __launch_bounds__(256) void fused_small1_kernel(
    const f16* __restrict__ fd2c, const f16* __restrict__ wqc,
    f16* __restrict__ catWqp,
    const f16* __restrict__ fc2T, f16* __restrict__ bt2)
{
    __shared__ __align__(16) f16 As[128 * 32];
    __shared__ __align__(16) f16 Bs[128 * 32];
    const int id = blockIdx.x;
    if (id < 4)
        gemm_tile(As, Bs, fd2c, wqc, catWqp, DM_, DM_, DM_, DM_, id & 1, id >> 1);
    else
        gemm_tile(As, Bs, fc2T, fd2c, bt2, DP_, DM_, DM_, 512, id - 4, 0);
}

// ---------------- fused small GEMMs 2: WallT (8 tiles) + folded biases (5 blocks) ----------------
__global__ __launch_bounds__(256) void fused_small2_kernel(
    const f16* __restrict__ catW, const f16* __restrict__ fc1c, f16* __restrict__ WallT,
    const float* __restrict__ fc1_b, const float* __restrict__ fd2_b,
    const float* __restrict__ fc2_w, const float* __restrict__ fc2_b,
    float* __restrict__ b_all, float* __restrict__ bias2)
{
    __shared__ __align__(16) f16 As[128 * 32];
    __shared__ __align__(16) f16 Bs[128 * 32];
    const int id = blockIdx.x;
    const int tid = threadIdx.x;
    if (id < 8) {
        gemm_tile(As, Bs, catW, fc1c, WallT, 1024, DP_, DM_, DP_, 0, id);
    } else if (id < 12) {
        const int n = (id - 8) * 256 + tid;
        float s = 0.0f;
        for (int j = 0; j < DM_; ++j)
            s += fc1_b[j] * (float)catW[(size_t)n * DM_ + j];
        b_all[n] = s;
    } else if (tid < DP_) {
        float s = fc2_b[tid];
        for (int t = 0; t < DM_; ++t)
            s += fd2_b[t] * fc2_w[(size_t)t * DP_ + tid];
        bias2[tid] = s;
    }
}

// ---------------- fused attention: linear-split MLP, packed f16 h, 16B uint4 gathers ----
__global__ __launch_bounds__(256, 1) void attn_kernel(
    const f16* __restrict__ qkv, const u8* __restrict__ kvw,
    const f16* __restrict__ ubuf, const int* __restrict__ knn_idx,
    const float* __restrict__ fd2_b,
    f16* __restrict__ ab)
{
    const int wave = threadIdx.x >> 6, l = threadIdx.x & 63;
    const int bi = blockIdx.x;
    const int p = ((bi & 3) << 12) + ((bi >> 2) << 2) + wave;   // batch-pinned remap
    const int c0 = l * 4;

    int gi = 0;
    if (l < 16) gi = knn_idx[p * K_ + l];

    // prefetch ALL 16 neighbor kvw rows (independent 16B loads), pin above compute
    uint4 kvr[16];
#pragma unroll
    for (int k = 0; k < 16; ++k) {
        const int gik = __shfl(gi, k);
        kvr[k] = *(const uint4*)(kvw + (size_t)gik * 1024 + l * 16);
    }
    asm volatile("" ::: "memory");

    const uint2 qu  = *(const uint2*)(qkv + (size_t)p * 1024 + c0);
    const uint2 qpu = *(const uint2*)(qkv + (size_t)p * 1024 + 768 + c0);
    const uint2 uu  = *(const uint2*)(ubuf + (size_t)p * 256 + c0);
    const h2 qh01 = ash2(qu.x), qh23 = ash2(qu.y);
    const h2 qp01 = ash2(qpu.x), qp23 = ash2(qpu.y);
    const h2 u01 = ash2(uu.x), u23 = ash2(uu.y);
    const float q0 = (float)qh01.x, q1 = (float)qh01.y, q2 = (float)qh23.x, q3 = (float)qh23.y;
    const h2 zero2 = (h2)(__fp16)0.0f;

    const float4 f2b = *(const float4*)&fd2_b[c0];

    // qb = q . fd2_b (constant over k)
    float qb;
    {
        float tq = q0 * f2b.x + q1 * f2b.y + q2 * f2b.z + q3 * f2b.w;
#pragma unroll
        for (int off = 1; off < 64; off <<= 1) tq += __shfl_xor(tq, off);
        qb = tq;
    }

    // phase 1: h = pk_max(u - w, 0) (2 packed ops per 4 dims); logits via dot2
    float lg[16];
    u32 h01r[16], h23r[16];
#pragma unroll
    for (int k = 0; k < 16; ++k) {
        const uint4 r = kvr[k];
        h2 d01 = u01 - ash2(r.z);
        h2 d23 = u23 - ash2(r.w);
        d01 = __builtin_elementwise_max(d01, zero2);
        d23 = __builtin_elementwise_max(d23, zero2);
        h01r[k] = asu32(d01); h23r[k] = asu32(d23);
        const auto k01 = __builtin_amdgcn_cvt_pk_f32_fp8((int)r.x, false);
        const auto k23 = __builtin_amdgcn_cvt_pk_f32_fp8((int)r.x, true);
        float t = q0 * k01[0] + q1 * k01[1] + q2 * k23[0] + q3 * k23[1];
        t = __builtin_amdgcn_fdot2(d01, qp01, t, false);
        t = __builtin_amdgcn_fdot2(d23, qp23, t, false);
#pragma unroll
        for (int off = 1; off < 64; off <<= 1) t += __shfl_xor(t, off);
        lg[k] = t;
    }

    // softmax over 16 (redundant per lane, all registers)
    float att[16];
    {
        float mx = -3.0e38f;
#pragma unroll
        for (int k = 0; k < 16; ++k) {
            att[k] = (lg[k] + qb) * (1.0f / 16.0f);
            mx = fmaxf(mx, att[k]);
        }
        float s = 0.0f;
#pragma unroll
        for (int k = 0; k < 16; ++k) { att[k] = __expf(att[k] - mx); s += att[k]; }
        const float inv = 1.0f / s;
#pragma unroll
        for (int k = 0; k < 16; ++k) att[k] *= inv;
    }

    // phase 2: pure VALU — rbar = sum att*v (kvr regs), hbar = sum att*h (regs)
    float rb[4] = {0, 0, 0, 0}, hb[4] = {0, 0, 0, 0};
#pragma unroll
    for (int k = 0; k < 16; ++k) {
        const auto v01 = __builtin_amdgcn_cvt_pk_f32_fp8((int)kvr[k].y, false);
        const auto v23 = __builtin_amdgcn_cvt_pk_f32_fp8((int)kvr[k].y, true);
        const h2 hh01 = ash2(h01r[k]), hh23 = ash2(h23r[k]);
        const float a = att[k];
        rb[0] = fmaf(a, v01[0], rb[0]);
        rb[1] = fmaf(a, v01[1], rb[1]);
        rb[2] = fmaf(a, v23[0], rb[2]);
        rb[3] = fmaf(a, v23[1], rb[3]);
        hb[0] = fmaf(a, (float)hh01.x, hb[0]);
        hb[1] = fmaf(a, (float)hh01.y, hb[1]);
        hb[2] = fmaf(a, (float)hh23.x, hb[2]);
        hb[3] = fmaf(a, (float)hh23.y, hb[3]);
    }

    const uint2 ho = make_uint2(asu32(pkrtz(hb[0], hb[1])), asu32(pkrtz(hb[2], hb[3])));
    const uint2 ro = make_uint2(asu32(pkrtz(rb[0], rb[1])), asu32(pkrtz(rb[2], rb[3])));
    *(uint2*)(ab + (size_t)p * 512 + c0) = ho;
    *(uint2*)(ab + (size_t)p * 512 + 256 + c0) = ro;
}

extern "C" void kernel_launch(void* const* d_in, const int* in_sizes, int n_in,
                              void* d_out, int out_size, void* d_ws, size_t ws_size,
                              hipStream_t stream)
{
    const float* features = (const float*)d_in[0];
    const float* xyz   = (const float*)d_in[1];
    const float* fc1_w = (const float*)d_in[2];
    const float* fc1_b = (const float*)d_in[3];
    const float* fc2_w = (const float*)d_in[4];
    const float* fc2_b = (const float*)d_in[5];
    const float* fd1_w = (const float*)d_in[6];
    const float* fd1_b = (const float*)d_in[7];
    const float* fd2_w = (const float*)d_in[8];
    const float* fd2_b = (const float*)d_in[9];
    const float* wq    = (const float*)d_in[10];
    const float* wk    = (const float*)d_in[11];
    const float* wv    = (const float*)d_in[12];
    float* out = (float*)d_out;

    char* base = (char*)d_ws;
    const size_t MB = 1024 * 1024;
    u32*  part = (u32*)(base + 0);                 // 16 MB (16 segs), dead after merge
    f16*  ab   = (f16*)(base + 0);                 // 16 MB [hbar|rbar]
    u8*   kvw  = (u8*)(base + 20 * MB);            // 16 MB {k fp8, v fp8, w f16} rows
    f16*  qkv  = (f16*)(base + 36 * MB);           // 32 MB (q/qp cols live)
    f16*  featb = (f16*)(base + 68 * MB);          // 4 MB
    int*  idx  = (int*)(base + 72 * MB);           // 1 MB
    char* wb = base + 73 * MB;
    f16* catW  = (f16*)(wb + 0);                   // 512 KB
    f16* WallT = (f16*)(wb + 512 * 1024);          // 256 KB
    f16* bt2   = (f16*)(wb + 768 * 1024);          // 128 KB
    f16* fd2c  = (f16*)(wb + 896 * 1024);
    f16* wqc   = (f16*)(wb + 1024 * 1024);
    f16* fc1c  = (f16*)(wb + 1152 * 1024);
    f16* fc2T  = (f16*)(wb + 1216 * 1024);
    float* b_all = (float*)(wb + 1280 * 1024);
    float* bias2 = (float*)(wb + 1284 * 1024);
    f16*  ubuf = (f16*)(base + 76 * MB);           // 8 MB u = xyz.fd1 + b (f16)

    const dim3 blk(256);

    // 1. prep casts (512 blocks) || KNN partial top-16 (1024 blocks)
    fused_prep_knn_kernel<<<dim3(512 + 1024), blk, 0, stream>>>(
        wq, wk, wv, fd2_w, fc1_w, fc2_w, features,
        catW, fc2T, bt2, fd2c, wqc, fc1c, featb, xyz, part);
    // 2. wqp -> catW rows 768.. (4 tiles) || bt2 cols [0,256) (2 tiles)
    fused_small1_kernel<<<dim3(6), blk, 0, stream>>>(fd2c, wqc, catW + 768 * 256, fc2T, bt2);
    // 3. WallT (8 tiles) || b_all (4) || bias2 (1)
    fused_small2_kernel<<<dim3(13), blk, 0, stream>>>(catW, fc1c, WallT,
                                                      fc1_b, fd2_b, fc2_w, fc2_b, b_all, bias2);
    // 4. qkv GEMM (kv stays in LDS -> fp8 kvw + ubuf fused) || KNN merge (64 blocks)
    gemm_qkv_fused_kernel<<<dim3(256 + 64), blk, 0, stream>>>(
        featb, WallT, b_all, xyz, fd1_w, fd1_b, qkv, kvw, ubuf, part, idx);
    // 5. fused attention -> ab = [hbar | rbar]  (XCD batch-pinned block remap)
    attn_kernel<<<dim3(NPTS / 4), blk, 0, stream>>>(qkv, kvw, ubuf, idx, fd2_b, ab);
    // 6. out GEMM: 64x128 tiles -> 256 blocks, fused transpose + bias + residual
    gemm_out_kernel<<<dim3(NPTS / 64), blk, 0, stream>>>(ab, bt2, bias2, features, out);

    (void)in_sizes; (void)n_in; (void)out_size; (void)ws_size;
}

// Round 7
// 203.304 us; speedup vs baseline: 1.0504x; 1.0504x over previous
//
#include <hip/hip_runtime.h>
#include <hip/hip_bf16.h>
#include <hip/hip_fp16.h>
#include <math.h>

#define B_   4
#define N_   4096
#define K_   16
#define DP_  128
#define DM_  256
#define NPTS (B_ * N_)
#define SEG_ 16
#define CAND_ (N_ / SEG_)   // 256 candidates per segment
#define QPAD 136            // K=128 LDS row stride (f16): 272B, uint4-aligned, low conflict

typedef unsigned int u32;
typedef unsigned char u8;
typedef _Float16 f16;
typedef __attribute__((ext_vector_type(2))) __fp16 h2;     // matches cvt_pkrtz ABI
typedef __attribute__((ext_vector_type(8))) _Float16 f16x8; // MFMA operand
typedef __attribute__((ext_vector_type(4))) float floatx4;

static __device__ __forceinline__ h2 pkrtz(float a, float b) {
    return __builtin_amdgcn_cvt_pkrtz(a, b);
}
static __device__ __forceinline__ u32 asu32(h2 h) { return __builtin_bit_cast(u32, h); }
static __device__ __forceinline__ h2 ash2(u32 u) { return __builtin_bit_cast(h2, u); }

// ---- bitonic primitives on u32 registers ----
#define CEXA(x, y) { u32 _lo = min(x, y); y = max(x, y); x = _lo; }   // x<=y
#define CEXD(x, y) { u32 _hi = max(x, y); y = min(x, y); x = _hi; }   // x>=y

// Batcher odd-even mergesort network, 16 elements, 63 comparators, depth 10.
// All comparators CEXD -> fully sorted DESCENDING.
static __device__ __forceinline__ void sort16_desc(u32 c[16]) {
    // L1
    CEXD(c[0],c[1]);  CEXD(c[2],c[3]);  CEXD(c[4],c[5]);  CEXD(c[6],c[7]);
    CEXD(c[8],c[9]);  CEXD(c[10],c[11]); CEXD(c[12],c[13]); CEXD(c[14],c[15]);
    // L2
    CEXD(c[0],c[2]);  CEXD(c[1],c[3]);  CEXD(c[4],c[6]);  CEXD(c[5],c[7]);
    CEXD(c[8],c[10]); CEXD(c[9],c[11]); CEXD(c[12],c[14]); CEXD(c[13],c[15]);
    // L3
    CEXD(c[1],c[2]);  CEXD(c[5],c[6]);  CEXD(c[9],c[10]); CEXD(c[13],c[14]);
    // L4
    CEXD(c[0],c[4]);  CEXD(c[1],c[5]);  CEXD(c[2],c[6]);  CEXD(c[3],c[7]);
    CEXD(c[8],c[12]); CEXD(c[9],c[13]); CEXD(c[10],c[14]); CEXD(c[11],c[15]);
    // L5
    CEXD(c[2],c[4]);  CEXD(c[3],c[5]);  CEXD(c[10],c[12]); CEXD(c[11],c[13]);
    // L6
    CEXD(c[1],c[2]);  CEXD(c[3],c[4]);  CEXD(c[5],c[6]);
    CEXD(c[9],c[10]); CEXD(c[11],c[12]); CEXD(c[13],c[14]);
    // L7 (merge 8+8)
    CEXD(c[0],c[8]);  CEXD(c[1],c[9]);  CEXD(c[2],c[10]); CEXD(c[3],c[11]);
    CEXD(c[4],c[12]); CEXD(c[5],c[13]); CEXD(c[6],c[14]); CEXD(c[7],c[15]);
    // L8
    CEXD(c[4],c[8]);  CEXD(c[5],c[9]);  CEXD(c[6],c[10]); CEXD(c[7],c[11]);
    // L9
    CEXD(c[2],c[4]);  CEXD(c[3],c[5]);  CEXD(c[6],c[8]);  CEXD(c[7],c[9]);
    CEXD(c[10],c[12]); CEXD(c[11],c[13]);
    // L10
    CEXD(c[1],c[2]);  CEXD(c[3],c[4]);  CEXD(c[5],c[6]);  CEXD(c[7],c[8]);
    CEXD(c[9],c[10]); CEXD(c[11],c[12]); CEXD(c[13],c[14]);
}

static __device__ __forceinline__ void remerge16_asc(u32 L[16]) {
    CEXA(L[0],L[8]);  CEXA(L[1],L[9]);  CEXA(L[2],L[10]); CEXA(L[3],L[11]);
    CEXA(L[4],L[12]); CEXA(L[5],L[13]); CEXA(L[6],L[14]); CEXA(L[7],L[15]);
    CEXA(L[0],L[4]);  CEXA(L[1],L[5]);  CEXA(L[2],L[6]);  CEXA(L[3],L[7]);
    CEXA(L[8],L[12]); CEXA(L[9],L[13]); CEXA(L[10],L[14]); CEXA(L[11],L[15]);
    CEXA(L[0],L[2]);  CEXA(L[1],L[3]);  CEXA(L[4],L[6]);  CEXA(L[5],L[7]);
    CEXA(L[8],L[10]); CEXA(L[9],L[11]); CEXA(L[12],L[14]); CEXA(L[13],L[15]);
    CEXA(L[0],L[1]);  CEXA(L[2],L[3]);  CEXA(L[4],L[5]);  CEXA(L[6],L[7]);
    CEXA(L[8],L[9]);  CEXA(L[10],L[11]); CEXA(L[12],L[13]); CEXA(L[14],L[15]);
}

// ---------------- KNN part body (R1 variant — best measured, 43.5 µs) ----------------
static __device__ void knn_part_body(float4* sc, const float* __restrict__ xyz,
                                     u32* __restrict__ part, int id)
{
    const int xblk = id & 15;            // N_/256 = 16
    const int s = (id >> 4) & 15;        // SEG_ = 16
    const int b = id >> 8;               // B_ = 4
    const int n = xblk * 256 + threadIdx.x;
    const float* xb = xyz + (size_t)b * N_ * 3;
    const float x0 = xb[n * 3 + 0], x1 = xb[n * 3 + 1], x2 = xb[n * 3 + 2];
    const float nx0 = -x0, nx1 = -x1, nx2 = -x2;
    // e = 0.5*|y|^2 - x.y + 0.5*|x|^2 = 0.5*d^2 >= 0 (up to rounding) -> raw
    // positive-float bits are a monotone sort key; fmax clamp protects the
    // self-point (rounding could make its e tiny-negative -> huge u32 key).
    const float hs = 0.5f * fmaf(x0, x0, fmaf(x1, x1, x2 * x2));
    const u32 kmask = 0xFFFFF000u;

    {
        const int m = s * CAND_ + threadIdx.x;   // CAND_ == 256 == blockDim.x
        const float a0 = xb[m * 3 + 0];
        const float a1 = xb[m * 3 + 1];
        const float a2 = xb[m * 3 + 2];
        sc[threadIdx.x] = make_float4(a0, a1, a2, 0.5f * (a0 * a0 + a1 * a1 + a2 * a2));
    }
    __syncthreads();

    u32 L[16];
#pragma unroll
    for (int i = 0; i < 16; ++i) L[i] = 0xFFFFFFFFu;

    const u32 ibase = (u32)(s * CAND_);
    for (int m0 = 0; m0 < CAND_; m0 += 16) {
        float4 cc[16];
#pragma unroll
        for (int t = 0; t < 16; ++t) cc[t] = sc[m0 + t];
        u32 c[16];
#pragma unroll
        for (int t = 0; t < 16; ++t) {
            const float e = fmaf(nx0, cc[t].x,
                            fmaf(nx1, cc[t].y,
                            fmaf(nx2, cc[t].z, cc[t].w + hs)));
            c[t] = (__float_as_uint(fmaxf(e, 0.0f)) & kmask) | (ibase + (u32)(m0 + t));
        }
        sort16_desc(c);
#pragma unroll
        for (int i = 0; i < 16; ++i) L[i] = min(L[i], c[i]);
        remerge16_asc(L);
    }

    const int p = b * N_ + n;
#pragma unroll
    for (int j = 0; j < 16; ++j)
        part[(size_t)(s * 16 + j) * NPTS + p] = L[j];
}

// ---------------- prep body: weight transpose-casts + straight casts (f16) ----------------
static __device__ void prep_body(float (*t)[33],
    const float* __restrict__ wq, const float* __restrict__ wk, const float* __restrict__ wv,
    const float* __restrict__ fd2, const float* __restrict__ fc1, const float* __restrict__ fc2,
    const float* __restrict__ feat,
    f16* __restrict__ catW, f16* __restrict__ fc2T, f16* __restrict__ bt2,
    f16* __restrict__ fd2c, f16* __restrict__ wqc, f16* __restrict__ fc1c,
    f16* __restrict__ featb, int bx, int by, int job)
{
    const int tid = threadIdx.x;

    if (job < 4) {
        const float* in; int R, C;
        switch (job) {
            case 0: in = wq;  R = DM_; C = DM_; break;
            case 1: in = wk;  R = DM_; C = DM_; break;
            case 2: in = wv;  R = DM_; C = DM_; break;
            default: in = fc2; R = DM_; C = DP_; break;
        }
        const int c0 = bx * 32, r0 = by * 32;
        if (c0 >= C || r0 >= R) return;
        const int lx = tid & 31, ly = tid >> 5;
#pragma unroll
        for (int i = 0; i < 32; i += 8)
            t[ly + i][lx] = in[(size_t)(r0 + ly + i) * C + c0 + lx];
        __syncthreads();
#pragma unroll
        for (int i = 0; i < 32; i += 8) {
            const int c = c0 + ly + i;
            const f16 v = (f16)t[lx][ly + i];
            int n;
            switch (job) {
                case 0: n = c; break;
                case 1: n = 256 + ((c >> 2) << 3) + (c & 3); break;
                case 2: n = 256 + ((c >> 2) << 3) + 4 + (c & 3); break;
                default: n = -1; break;
            }
            if (job < 3) {
                catW[(size_t)n * DM_ + r0 + lx] = v;
            } else {
                fc2T[(size_t)c * DM_ + r0 + lx] = v;
                bt2[(size_t)c * 512 + 256 + r0 + lx] = v;
            }
        }
    } else {
        const int bid = by * 8 + bx;                      // 0..63
        const int tId = bid * 256 + tid;
        const float* in; f16* outp; int n4;
        if (job == 4)      { in = fd2;  outp = fd2c;  n4 = (DM_ * DM_) / 4; }
        else if (job == 5) { in = wq;   outp = wqc;   n4 = (DM_ * DM_) / 4; }
        else if (job == 6) { in = fc1;  outp = fc1c;  n4 = (DP_ * DM_) / 4; }
        else               { in = feat; outp = featb; n4 = (NPTS * DP_) / 4; }
        for (int i = tId; i < n4; i += 16384) {
            const float4 v = ((const float4*)in)[i];
            const u32 lo = asu32(pkrtz(v.x, v.y));
            const u32 hi = asu32(pkrtz(v.z, v.w));
            ((uint2*)outp)[i] = make_uint2(lo, hi);
        }
    }
}

// ---------------- FUSED prep (512 blocks) + knn_part (1024 blocks) ----------------
__global__ __launch_bounds__(256) void fused_prep_knn_kernel(
    const float* __restrict__ wq, const float* __restrict__ wk, const float* __restrict__ wv,
    const float* __restrict__ fd2, const float* __restrict__ fc1, const float* __restrict__ fc2,
    const float* __restrict__ feat,
    f16* __restrict__ catW, f16* __restrict__ fc2T, f16* __restrict__ bt2,
    f16* __restrict__ fd2c, f16* __restrict__ wqc, f16* __restrict__ fc1c,
    f16* __restrict__ featb,
    const float* __restrict__ xyz, u32* __restrict__ part)
{
    __shared__ __align__(16) char smem[4352];
    const int id = blockIdx.x;
    if (id < 512) {
        prep_body((float(*)[33])smem, wq, wk, wv, fd2, fc1, fc2, feat,
                  catW, fc2T, bt2, fd2c, wqc, fc1c, featb,
                  id & 7, (id >> 3) & 7, id >> 6);
    } else {
        knn_part_body((float4*)smem, xyz, part, id - 512);
    }
}

// ---------------- generic BK=32 GEMM tile (C[M,N] = A@Bt^T, f16 out) ----------------
static __device__ void gemm_tile(f16* As, f16* Bs,
    const f16* __restrict__ A, const f16* __restrict__ Bt,
    f16* __restrict__ Cb,
    int M, int N, int K, int ldc, int bx, int by)
{
    const int tid = threadIdx.x;
    const int m0 = by * 128, n0 = bx * 128;
    const int w = tid >> 6, l = tid & 63;
    const int wm = (w >> 1) * 64, wn = (w & 1) * 64;
    const int fm = l & 15, kq = l >> 4;

    floatx4 acc[4][4];
#pragma unroll
    for (int i = 0; i < 4; ++i)
#pragma unroll
        for (int j = 0; j < 4; ++j)
            acc[i][j] = (floatx4){0.0f, 0.0f, 0.0f, 0.0f};

    for (int k0 = 0; k0 < K; k0 += 32) {
        __syncthreads();
#pragma unroll
        for (int c = 0; c < 2; ++c) {
            const int li = tid + c * 256;
            const int row = li >> 2, part = li & 3;
            *(uint4*)&As[row * 32 + part * 8] =
                *(const uint4*)&A[(size_t)(m0 + row) * K + k0 + part * 8];
            *(uint4*)&Bs[row * 32 + part * 8] =
                *(const uint4*)&Bt[(size_t)(n0 + row) * K + k0 + part * 8];
        }
        __syncthreads();
        f16x8 af[4], bf[4];
#pragma unroll
        for (int i = 0; i < 4; ++i)
            af[i] = *(const f16x8*)&As[(wm + i * 16 + fm) * 32 + kq * 8];
#pragma unroll
        for (int j = 0; j < 4; ++j)
            bf[j] = *(const f16x8*)&Bs[(wn + j * 16 + fm) * 32 + kq * 8];
#pragma unroll
        for (int i = 0; i < 4; ++i)
#pragma unroll
            for (int j = 0; j < 4; ++j)
                acc[i][j] = __builtin_amdgcn_mfma_f32_16x16x32_f16(af[i], bf[j], acc[i][j], 0, 0, 0);
    }

#pragma unroll
    for (int i = 0; i < 4; ++i) {
#pragma unroll
        for (int j = 0; j < 4; ++j) {
            const int col = n0 + wn + j * 16 + fm;
            const int rowb = m0 + wm + i * 16 + kq * 4;
#pragma unroll
            for (int r = 0; r < 4; ++r)
                Cb[(size_t)(rowb + r) * ldc + col] = (f16)acc[i][j][r];
        }
    }
}

static __device__ void mergeAB_body(const u32* __restrict__ part, int* __restrict__ knn_idx,
                                    int id)
{
    const int p = id * 256 + threadIdx.x;
    const int b = p >> 12;

    u32 L[16];
#pragma unroll
    for (int i = 0; i < 16; ++i) L[i] = 0xFFFFFFFFu;

    for (int s = 0; s < SEG_; ++s) {
        u32 seg[16];
#pragma unroll
        for (int j = 0; j < 16; ++j)
            seg[j] = part[(size_t)(s * 16 + j) * NPTS + p];
#pragma unroll
        for (int i = 0; i < 16; ++i) L[i] = min(L[i], seg[15 - i]);
        remerge16_asc(L);
    }

    int* o = knn_idx + (size_t)p * K_;
#pragma unroll
    for (int i = 0; i < 16; ++i) o[i] = b * N_ + (int)(L[i] & 0xFFFu);
}

// ---------------- qkv GEMM, 32-row x 1024-col blocks, per-tile kvw/ubuf pack ----------
// Block computes all 1024 output cols for 32 rows (B streamed through LDS).
// kv n-tiles (cols 256..767, 16 groups per 128-col tile) are staged per-tile in
// a small LDS buffer then packed directly to fp8 kvw rows + w/u vectors -- the
// kv cols never touch HBM as f16. LDS total 52 KB -> 2 blocks/CU at grid 512
// (vs round-6's 119 KB / 1 block/CU, which stalled the serialized B-panel loop).
// Blocks 512.. run the 16-segment KNN merge (fused to save a launch).
__global__ __launch_bounds__(256) void gemm_qkv_fused_kernel(
    const f16* __restrict__ A,     // featb [NPTS][128]
    const f16* __restrict__ Bt,    // WallT [1024][128]
    const float* __restrict__ bias,
    const float* __restrict__ xyz,
    const float* __restrict__ fd1_w, const float* __restrict__ fd1_b,
    f16* __restrict__ Cb,          // qkv [NPTS][1024] (q/qp cols only)
    u8* __restrict__ kvw, f16* __restrict__ ubuf,
    const u32* __restrict__ part, int* __restrict__ knn_idx)
{
    __shared__ __align__(16) f16 As[32 * 136];
    __shared__ __align__(16) f16 Bs[128 * 136];
    __shared__ __align__(16) f16 kvstage[32 * 136];
    const int bid = blockIdx.x;
    if (bid >= 512) { mergeAB_body(part, knn_idx, bid - 512); return; }

    const int tid = threadIdx.x;
    const int m0 = bid * 32;
    const int w = tid >> 6, l = tid & 63;
    const int wr = (w >> 1) * 16;          // wave row offset within 32
    const int wn = (w & 1) * 64;           // wave col offset within 128-tile
    const int fm = l & 15, kq = l >> 4;

    // stage A rows m0..m0+31: 32 rows x 16 uint4-chunks = 512 slots
#pragma unroll
    for (int c = 0; c < 2; ++c) {
        const int li = tid + c * 256;      // 0..511
        const int row = li >> 4, pt = li & 15;
        *(uint4*)&As[row * 136 + pt * 8] =
            *(const uint4*)&A[(size_t)(m0 + row) * 128 + pt * 8];
    }

    for (int nt = 0; nt < 8; ++nt) {
        __syncthreads();   // As ready (iter 0) / prior Bs + kvstage reads done
        // stage B rows nt*128..+127: 128 rows x 16 chunks = 2048 slots
#pragma unroll
        for (int c = 0; c < 8; ++c) {
            const int li = tid + c * 256;  // 0..2047
            const int row = li >> 4, pt = li & 15;
            *(uint4*)&Bs[row * 136 + pt * 8] =
                *(const uint4*)&Bt[(size_t)(nt * 128 + row) * 128 + pt * 8];
        }
        __syncthreads();

        floatx4 acc[4];
#pragma unroll
        for (int j = 0; j < 4; ++j)
            acc[j] = (floatx4){0.0f, 0.0f, 0.0f, 0.0f};

#pragma unroll
        for (int kk = 0; kk < 4; ++kk) {
            f16x8 af, bf[4];
            af = *(const f16x8*)&As[(wr + fm) * 136 + kk * 32 + kq * 8];
#pragma unroll
            for (int j = 0; j < 4; ++j)
                bf[j] = *(const f16x8*)&Bs[(wn + j * 16 + fm) * 136 + kk * 32 + kq * 8];
#pragma unroll
            for (int j = 0; j < 4; ++j)
                acc[j] = __builtin_amdgcn_mfma_f32_16x16x32_f16(af, bf[j], acc[j], 0, 0, 0);
        }

        if (nt >= 2 && nt < 6) {
            // kv tile: stage f16 (identical rounding to the old global
            // round-trip), then pack this tile's 16 groups to kvw + ubuf.
#pragma unroll
            for (int j = 0; j < 4; ++j) {
                const int col = nt * 128 + wn + j * 16 + fm;
                const int lcol = col - nt * 128;           // 0..127
                const int rowb = wr + kq * 4;
#pragma unroll
                for (int r = 0; r < 4; ++r)
                    kvstage[(rowb + r) * 136 + lcol] = (f16)(acc[j][r] + bias[col]);
            }
            __syncthreads();   // kvstage complete

            // pack: 32 rows x 16 groups = 512 tasks, 2 per thread
#pragma unroll
            for (int it = 0; it < 2; ++it) {
                const int task = it * 256 + tid;
                const int pl = task >> 4, gl = task & 15;
                const int p = m0 + pl;
                const int g = (nt - 2) * 16 + gl;          // global group 0..63
                const uint4 kv = *(const uint4*)&kvstage[pl * 136 + gl * 8];
                const h2 k01 = ash2(kv.x), k23 = ash2(kv.y);
                const h2 v01 = ash2(kv.z), v23 = ash2(kv.w);
                int lo = 0, hi = 0;
                lo = __builtin_amdgcn_cvt_pk_fp8_f32((float)k01.x, (float)k01.y, lo, false);
                lo = __builtin_amdgcn_cvt_pk_fp8_f32((float)k23.x, (float)k23.y, lo, true);
                hi = __builtin_amdgcn_cvt_pk_fp8_f32((float)v01.x, (float)v01.y, hi, false);
                hi = __builtin_amdgcn_cvt_pk_fp8_f32((float)v23.x, (float)v23.y, hi, true);

                const float x0 = xyz[(size_t)p * 3 + 0];
                const float x1 = xyz[(size_t)p * 3 + 1];
                const float x2 = xyz[(size_t)p * 3 + 2];
                const int c0 = g * 4;
                const float4 w0v = *(const float4*)&fd1_w[c0];
                const float4 w1v = *(const float4*)&fd1_w[DM_ + c0];
                const float4 w2v = *(const float4*)&fd1_w[2 * DM_ + c0];
                const float4 b1v = *(const float4*)&fd1_b[c0];
                const float ww0 = x0 * w0v.x + x1 * w1v.x + x2 * w2v.x;
                const float ww1 = x0 * w0v.y + x1 * w1v.y + x2 * w2v.y;
                const float ww2 = x0 * w0v.z + x1 * w1v.z + x2 * w2v.z;
                const float ww3 = x0 * w0v.w + x1 * w1v.w + x2 * w2v.w;

                uint4 row;
                row.x = (u32)lo;
                row.y = (u32)hi;
                row.z = asu32(pkrtz(ww0, ww1));
                row.w = asu32(pkrtz(ww2, ww3));
                *(uint4*)(kvw + (size_t)p * 1024 + g * 16) = row;

                const uint2 uu = make_uint2(asu32(pkrtz(ww0 + b1v.x, ww1 + b1v.y)),
                                            asu32(pkrtz(ww2 + b1v.z, ww3 + b1v.w)));
                *(uint2*)(ubuf + (size_t)p * 256 + c0) = uu;
            }
        } else {
            // q / qp tile: write to qkv as before
#pragma unroll
            for (int j = 0; j < 4; ++j) {
                const int col = nt * 128 + wn + j * 16 + fm;
                const int rowb = m0 + wr + kq * 4;
#pragma unroll
                for (int r = 0; r < 4; ++r)
                    Cb[(size_t)(rowb + r) * 1024 + col] = (f16)(acc[j][r] + bias[col]);
            }
        }
    }
}

// ---------------- out GEMM: 64x128 tile (256 blocks — full CU coverage) ----------------
__global__ __launch_bounds__(256) void gemm_out_kernel(
    const f16* __restrict__ A,      // ab [NPTS][512]
    const f16* __restrict__ Bt,     // bt2 [128][512]
    const float* __restrict__ bias2,
    const float* __restrict__ feat, // [NPTS][128] fp32
    float* __restrict__ CT)         // [B][DP][N]
{
    __shared__ __align__(16) f16 As[64 * 32];
    __shared__ __align__(16) f16 Bs[128 * 32];
    const int tid = threadIdx.x;
    const int m0 = blockIdx.x * 64;
    const int w = tid >> 6, l = tid & 63;
    const int wn = w * 32;
    const int fm = l & 15, kq = l >> 4;

    floatx4 acc[4][2];
#pragma unroll
    for (int i = 0; i < 4; ++i)
#pragma unroll
        for (int j = 0; j < 2; ++j)
            acc[i][j] = (floatx4){0.0f, 0.0f, 0.0f, 0.0f};

    for (int k0 = 0; k0 < 512; k0 += 32) {
        __syncthreads();
        {
            const int row = tid >> 2, part = tid & 3;
            *(uint4*)&As[row * 32 + part * 8] =
                *(const uint4*)&A[(size_t)(m0 + row) * 512 + k0 + part * 8];
        }
#pragma unroll
        for (int c = 0; c < 2; ++c) {
            const int li = tid + c * 256;
            const int row = li >> 2, part = li & 3;
            *(uint4*)&Bs[row * 32 + part * 8] =
                *(const uint4*)&Bt[(size_t)row * 512 + k0 + part * 8];
        }
        __syncthreads();
        f16x8 af[4], bf[2];
#pragma unroll
        for (int i = 0; i < 4; ++i)
            af[i] = *(const f16x8*)&As[(i * 16 + fm) * 32 + kq * 8];
#pragma unroll
        for (int j = 0; j < 2; ++j)
            bf[j] = *(const f16x8*)&Bs[(wn + j * 16 + fm) * 32 + kq * 8];
#pragma unroll
        for (int i = 0; i < 4; ++i)
#pragma unroll
            for (int j = 0; j < 2; ++j)
                acc[i][j] = __builtin_amdgcn_mfma_f32_16x16x32_f16(af[i], bf[j], acc[i][j], 0, 0, 0);
    }

#pragma unroll
    for (int i = 0; i < 4; ++i) {
#pragma unroll
        for (int j = 0; j < 2; ++j) {
            const int col = wn + j * 16 + fm;
            const int rowb = m0 + i * 16 + kq * 4;
            float4 vv;
#pragma unroll
            for (int r = 0; r < 4; ++r)
                ((float*)&vv)[r] = acc[i][j][r] + bias2[col]
                                 + feat[(size_t)(rowb + r) * DP_ + col];
            const int bb = rowb >> 12;
            *(float4*)&CT[(size_t)(bb * DP_ + col) * N_ + (rowb & (N_ - 1))] = vv;
        }
    }
}

// ---------------- fused small GEMMs 1: wqp (4 tiles) + bt2 (2 tiles) ----------------
__global__ __launch_bounds__(256) void fused_small1_kernel(
    const f16* __restrict__ fd2c, const f16* __restrict__ wqc,
    f16* __restrict__ catWqp,
    const f16* __restrict__ fc2T, f16* __restrict__ bt2)
{
    __shared__ __align__(16) f16 As[128 * 32];
    __shared__ __align__(16) f16 Bs[128 * 32];
    const int id = blockIdx.x;
    if (id < 4)
        gemm_tile(As, Bs, fd2c, wqc, catWqp, DM_, DM_, DM_, DM_, id & 1, id >> 1);
    else
        gemm_tile(As, Bs, fc2T, fd2c, bt2, DP_, DM_, DM_, 512, id - 4, 0);
}

// ---------------- fused small GEMMs 2: WallT (8 tiles) + folded biases (5 blocks) ----------------
__global__ __launch_bounds__(256) void fused_small2_kernel(
    const f16* __restrict__ catW, const f16* __restrict__ fc1c, f16* __restrict__ WallT,
    const float* __restrict__ fc1_b, const float* __restrict__ fd2_b,
    const float* __restrict__ fc2_w, const float* __restrict__ fc2_b,
    float* __restrict__ b_all, float* __restrict__ bias2)
{
    __shared__ __align__(16) f16 As[128 * 32];
    __shared__ __align__(16) f16 Bs[128 * 32];
    const int id = blockIdx.x;
    const int tid = threadIdx.x;
    if (id < 8) {
        gemm_tile(As, Bs, catW, fc1c, WallT, 1024, DP_, DM_, DP_, 0, id);
    } else if (id < 12) {
        const int n = (id - 8) * 256 + tid;
        float s = 0.0f;
        for (int j = 0; j < DM_; ++j)
            s += fc1_b[j] * (float)catW[(size_t)n * DM_ + j];
        b_all[n] = s;
    } else if (tid < DP_) {
        float s = fc2_b[tid];
        for (int t = 0; t < DM_; ++t)
            s += fd2_b[t] * fc2_w[(size_t)t * DP_ + tid];
        bias2[tid] = s;
    }
}

// ---------------- fused attention: linear-split MLP, packed f16 h, 16B uint4 gathers ----
__global__ __launch_bounds__(256, 1) void attn_kernel(
    const f16* __restrict__ qkv, const u8* __restrict__ kvw,
    const f16* __restrict__ ubuf, const int* __restrict__ knn_idx,
    const float* __restrict__ fd2_b,
    f16* __restrict__ ab)
{
    const int wave = threadIdx.x >> 6, l = threadIdx.x & 63;
    const int bi = blockIdx.x;
    const int p = ((bi & 3) << 12) + ((bi >> 2) << 2) + wave;   // batch-pinned remap
    const int c0 = l * 4;

    int gi = 0;
    if (l < 16) gi = knn_idx[p * K_ + l];

    // prefetch ALL 16 neighbor kvw rows (independent 16B loads), pin above compute
    uint4 kvr[16];
#pragma unroll
    for (int k = 0; k < 16; ++k) {
        const int gik = __shfl(gi, k);
        kvr[k] = *(const uint4*)(kvw + (size_t)gik * 1024 + l * 16);
    }
    asm volatile("" ::: "memory");

    const uint2 qu  = *(const uint2*)(qkv + (size_t)p * 1024 + c0);
    const uint2 qpu = *(const uint2*)(qkv + (size_t)p * 1024 + 768 + c0);
    const uint2 uu  = *(const uint2*)(ubuf + (size_t)p * 256 + c0);
    const h2 qh01 = ash2(qu.x), qh23 = ash2(qu.y);
    const h2 qp01 = ash2(qpu.x), qp23 = ash2(qpu.y);
    const h2 u01 = ash2(uu.x), u23 = ash2(uu.y);
    const float q0 = (float)qh01.x, q1 = (float)qh01.y, q2 = (float)qh23.x, q3 = (float)qh23.y;
    const h2 zero2 = (h2)(__fp16)0.0f;

    const float4 f2b = *(const float4*)&fd2_b[c0];

    // qb = q . fd2_b (constant over k)
    float qb;
    {
        float tq = q0 * f2b.x + q1 * f2b.y + q2 * f2b.z + q3 * f2b.w;
#pragma unroll
        for (int off = 1; off < 64; off <<= 1) tq += __shfl_xor(tq, off);
        qb = tq;
    }

    // phase 1: h = pk_max(u - w, 0) (2 packed ops per 4 dims); logits via dot2
    float lg[16];
    u32 h01r[16], h23r[16];
#pragma unroll
    for (int k = 0; k < 16; ++k) {
        const uint4 r = kvr[k];
        h2 d01 = u01 - ash2(r.z);
        h2 d23 = u23 - ash2(r.w);
        d01 = __builtin_elementwise_max(d01, zero2);
        d23 = __builtin_elementwise_max(d23, zero2);
        h01r[k] = asu32(d01); h23r[k] = asu32(d23);
        const auto k01 = __builtin_amdgcn_cvt_pk_f32_fp8((int)r.x, false);
        const auto k23 = __builtin_amdgcn_cvt_pk_f32_fp8((int)r.x, true);
        float t = q0 * k01[0] + q1 * k01[1] + q2 * k23[0] + q3 * k23[1];
        t = __builtin_amdgcn_fdot2(d01, qp01, t, false);
        t = __builtin_amdgcn_fdot2(d23, qp23, t, false);
#pragma unroll
        for (int off = 1; off < 64; off <<= 1) t += __shfl_xor(t, off);
        lg[k] = t;
    }

    // softmax over 16 (redundant per lane, all registers)
    float att[16];
    {
        float mx = -3.0e38f;
#pragma unroll
        for (int k = 0; k < 16; ++k) {
            att[k] = (lg[k] + qb) * (1.0f / 16.0f);
            mx = fmaxf(mx, att[k]);
        }
        float s = 0.0f;
#pragma unroll
        for (int k = 0; k < 16; ++k) { att[k] = __expf(att[k] - mx); s += att[k]; }
        const float inv = 1.0f / s;
#pragma unroll
        for (int k = 0; k < 16; ++k) att[k] *= inv;
    }

    // phase 2: pure VALU — rbar = sum att*v (kvr regs), hbar = sum att*h (regs)
    float rb[4] = {0, 0, 0, 0}, hb[4] = {0, 0, 0, 0};
#pragma unroll
    for (int k = 0; k < 16; ++k) {
        const auto v01 = __builtin_amdgcn_cvt_pk_f32_fp8((int)kvr[k].y, false);
        const auto v23 = __builtin_amdgcn_cvt_pk_f32_fp8((int)kvr[k].y, true);
        const h2 hh01 = ash2(h01r[k]), hh23 = ash2(h23r[k]);
        const float a = att[k];
        rb[0] = fmaf(a, v01[0], rb[0]);
        rb[1] = fmaf(a, v01[1], rb[1]);
        rb[2] = fmaf(a, v23[0], rb[2]);
        rb[3] = fmaf(a, v23[1], rb[3]);
        hb[0] = fmaf(a, (float)hh01.x, hb[0]);
        hb[1] = fmaf(a, (float)hh01.y, hb[1]);
        hb[2] = fmaf(a, (float)hh23.x, hb[2]);
        hb[3] = fmaf(a, (float)hh23.y, hb[3]);
    }

    const uint2 ho = make_uint2(asu32(pkrtz(hb[0], hb[1])), asu32(pkrtz(hb[2], hb[3])));
    const uint2 ro = make_uint2(asu32(pkrtz(rb[0], rb[1])), asu32(pkrtz(rb[2], rb[3])));
    *(uint2*)(ab + (size_t)p * 512 + c0) = ho;
    *(uint2*)(ab + (size_t)p * 512 + 256 + c0) = ro;
}

extern "C" void kernel_launch(void* const* d_in, const int* in_sizes, int n_in,
                              void* d_out, int out_size, void* d_ws, size_t ws_size,
                              hipStream_t stream)
{
    const float* features = (const float*)d_in[0];
    const float* xyz   = (const float*)d_in[1];
    const float* fc1_w = (const float*)d_in[2];
    const float* fc1_b = (const float*)d_in[3];
    const float* fc2_w = (const float*)d_in[4];
    const float* fc2_b = (const float*)d_in[5];
    const float* fd1_w = (const float*)d_in[6];
    const float* fd1_b = (const float*)d_in[7];
    const float* fd2_w = (const float*)d_in[8];
    const float* fd2_b = (const float*)d_in[9];
    const float* wq    = (const float*)d_in[10];
    const float* wk    = (const float*)d_in[11];
    const float* wv    = (const float*)d_in[12];
    float* out = (float*)d_out;

    char* base = (char*)d_ws;
    const size_t MB = 1024 * 1024;
    u32*  part = (u32*)(base + 0);                 // 16 MB (16 segs), dead after merge
    f16*  ab   = (f16*)(base + 0);                 // 16 MB [hbar|rbar]
    u8*   kvw  = (u8*)(base + 20 * MB);            // 16 MB {k fp8, v fp8, w f16} rows
    f16*  qkv  = (f16*)(base + 36 * MB);           // 32 MB (q/qp cols live)
    f16*  featb = (f16*)(base + 68 * MB);          // 4 MB
    int*  idx  = (int*)(base + 72 * MB);           // 1 MB
    char* wb = base + 73 * MB;
    f16* catW  = (f16*)(wb + 0);                   // 512 KB
    f16* WallT = (f16*)(wb + 512 * 1024);          // 256 KB
    f16* bt2   = (f16*)(wb + 768 * 1024);          // 128 KB
    f16* fd2c  = (f16*)(wb + 896 * 1024);
    f16* wqc   = (f16*)(wb + 1024 * 1024);
    f16* fc1c  = (f16*)(wb + 1152 * 1024);
    f16* fc2T  = (f16*)(wb + 1216 * 1024);
    float* b_all = (float*)(wb + 1280 * 1024);
    float* bias2 = (float*)(wb + 1284 * 1024);
    f16*  ubuf = (f16*)(base + 76 * MB);           // 8 MB u = xyz.fd1 + b (f16)

    const dim3 blk(256);

    // 1. prep casts (512 blocks) || KNN partial top-16 (1024 blocks)
    fused_prep_knn_kernel<<<dim3(512 + 1024), blk, 0, stream>>>(
        wq, wk, wv, fd2_w, fc1_w, fc2_w, features,
        catW, fc2T, bt2, fd2c, wqc, fc1c, featb, xyz, part);
    // 2. wqp -> catW rows 768.. (4 tiles) || bt2 cols [0,256) (2 tiles)
    fused_small1_kernel<<<dim3(6), blk, 0, stream>>>(fd2c, wqc, catW + 768 * 256, fc2T, bt2);
    // 3. WallT (8 tiles) || b_all (4) || bias2 (1)
    fused_small2_kernel<<<dim3(13), blk, 0, stream>>>(catW, fc1c, WallT,
                                                      fc1_b, fd2_b, fc2_w, fc2_b, b_all, bias2);
    // 4. qkv GEMM BM=32 (kv -> per-tile fp8 pack in LDS) || KNN merge (64 blocks)
    gemm_qkv_fused_kernel<<<dim3(512 + 64), blk, 0, stream>>>(
        featb, WallT, b_all, xyz, fd1_w, fd1_b, qkv, kvw, ubuf, part, idx);
    // 5. fused attention -> ab = [hbar | rbar]  (XCD batch-pinned block remap)
    attn_kernel<<<dim3(NPTS / 4), blk, 0, stream>>>(qkv, kvw, ubuf, idx, fd2_b, ab);
    // 6. out GEMM: 64x128 tiles -> 256 blocks, fused transpose + bias + residual
    gemm_out_kernel<<<dim3(NPTS / 64), blk, 0, stream>>>(ab, bt2, bias2, features, out);

    (void)in_sizes; (void)n_in; (void)out_size; (void)ws_size;
}

// Round 8
// 200.899 us; speedup vs baseline: 1.0630x; 1.0120x over previous
//
#include <hip/hip_runtime.h>
#include <hip/hip_bf16.h>
#include <hip/hip_fp16.h>
#include <math.h>

#define B_   4
#define N_   4096
#define K_   16
#define DP_  128
#define DM_  256
#define NPTS (B_ * N_)
#define SEG_ 16
#define CAND_ (N_ / SEG_)   // 256 candidates per segment
#define QPAD 136            // K=128 LDS row stride (f16): 272B, uint4-aligned, low conflict

typedef unsigned int u32;
typedef unsigned char u8;
typedef _Float16 f16;
typedef __attribute__((ext_vector_type(2))) __fp16 h2;     // matches cvt_pkrtz ABI
typedef __attribute__((ext_vector_type(8))) _Float16 f16x8; // MFMA operand
typedef __attribute__((ext_vector_type(4))) float floatx4;

static __device__ __forceinline__ h2 pkrtz(float a, float b) {
    return __builtin_amdgcn_cvt_pkrtz(a, b);
}
static __device__ __forceinline__ u32 asu32(h2 h) { return __builtin_bit_cast(u32, h); }
static __device__ __forceinline__ h2 ash2(u32 u) { return __builtin_bit_cast(h2, u); }

// ---- bitonic primitives on u32 registers ----
#define CEXA(x, y) { u32 _lo = min(x, y); y = max(x, y); x = _lo; }   // x<=y
#define CEXD(x, y) { u32 _hi = max(x, y); y = min(x, y); x = _hi; }   // x>=y

// Batcher odd-even mergesort network, 16 elements, 63 comparators, depth 10.
// All comparators CEXD -> fully sorted DESCENDING.
static __device__ __forceinline__ void sort16_desc(u32 c[16]) {
    // L1
    CEXD(c[0],c[1]);  CEXD(c[2],c[3]);  CEXD(c[4],c[5]);  CEXD(c[6],c[7]);
    CEXD(c[8],c[9]);  CEXD(c[10],c[11]); CEXD(c[12],c[13]); CEXD(c[14],c[15]);
    // L2
    CEXD(c[0],c[2]);  CEXD(c[1],c[3]);  CEXD(c[4],c[6]);  CEXD(c[5],c[7]);
    CEXD(c[8],c[10]); CEXD(c[9],c[11]); CEXD(c[12],c[14]); CEXD(c[13],c[15]);
    // L3
    CEXD(c[1],c[2]);  CEXD(c[5],c[6]);  CEXD(c[9],c[10]); CEXD(c[13],c[14]);
    // L4
    CEXD(c[0],c[4]);  CEXD(c[1],c[5]);  CEXD(c[2],c[6]);  CEXD(c[3],c[7]);
    CEXD(c[8],c[12]); CEXD(c[9],c[13]); CEXD(c[10],c[14]); CEXD(c[11],c[15]);
    // L5
    CEXD(c[2],c[4]);  CEXD(c[3],c[5]);  CEXD(c[10],c[12]); CEXD(c[11],c[13]);
    // L6
    CEXD(c[1],c[2]);  CEXD(c[3],c[4]);  CEXD(c[5],c[6]);
    CEXD(c[9],c[10]); CEXD(c[11],c[12]); CEXD(c[13],c[14]);
    // L7 (merge 8+8)
    CEXD(c[0],c[8]);  CEXD(c[1],c[9]);  CEXD(c[2],c[10]); CEXD(c[3],c[11]);
    CEXD(c[4],c[12]); CEXD(c[5],c[13]); CEXD(c[6],c[14]); CEXD(c[7],c[15]);
    // L8
    CEXD(c[4],c[8]);  CEXD(c[5],c[9]);  CEXD(c[6],c[10]); CEXD(c[7],c[11]);
    // L9
    CEXD(c[2],c[4]);  CEXD(c[3],c[5]);  CEXD(c[6],c[8]);  CEXD(c[7],c[9]);
    CEXD(c[10],c[12]); CEXD(c[11],c[13]);
    // L10
    CEXD(c[1],c[2]);  CEXD(c[3],c[4]);  CEXD(c[5],c[6]);  CEXD(c[7],c[8]);
    CEXD(c[9],c[10]); CEXD(c[11],c[12]); CEXD(c[13],c[14]);
}

static __device__ __forceinline__ void remerge16_asc(u32 L[16]) {
    CEXA(L[0],L[8]);  CEXA(L[1],L[9]);  CEXA(L[2],L[10]); CEXA(L[3],L[11]);
    CEXA(L[4],L[12]); CEXA(L[5],L[13]); CEXA(L[6],L[14]); CEXA(L[7],L[15]);
    CEXA(L[0],L[4]);  CEXA(L[1],L[5]);  CEXA(L[2],L[6]);  CEXA(L[3],L[7]);
    CEXA(L[8],L[12]); CEXA(L[9],L[13]); CEXA(L[10],L[14]); CEXA(L[11],L[15]);
    CEXA(L[0],L[2]);  CEXA(L[1],L[3]);  CEXA(L[4],L[6]);  CEXA(L[5],L[7]);
    CEXA(L[8],L[10]); CEXA(L[9],L[11]); CEXA(L[12],L[14]); CEXA(L[13],L[15]);
    CEXA(L[0],L[1]);  CEXA(L[2],L[3]);  CEXA(L[4],L[5]);  CEXA(L[6],L[7]);
    CEXA(L[8],L[9]);  CEXA(L[10],L[11]); CEXA(L[12],L[13]); CEXA(L[14],L[15]);
}

// ---------------- KNN part body (R1 variant — best measured, 43.5 µs) ----------------
static __device__ void knn_part_body(float4* sc, const float* __restrict__ xyz,
                                     u32* __restrict__ part, int id)
{
    const int xblk = id & 15;            // N_/256 = 16
    const int s = (id >> 4) & 15;        // SEG_ = 16
    const int b = id >> 8;               // B_ = 4
    const int n = xblk * 256 + threadIdx.x;
    const float* xb = xyz + (size_t)b * N_ * 3;
    const float x0 = xb[n * 3 + 0], x1 = xb[n * 3 + 1], x2 = xb[n * 3 + 2];
    const float nx0 = -x0, nx1 = -x1, nx2 = -x2;
    // e = 0.5*|y|^2 - x.y + 0.5*|x|^2 = 0.5*d^2 >= 0 (up to rounding) -> raw
    // positive-float bits are a monotone sort key; fmax clamp protects the
    // self-point (rounding could make its e tiny-negative -> huge u32 key).
    const float hs = 0.5f * fmaf(x0, x0, fmaf(x1, x1, x2 * x2));
    const u32 kmask = 0xFFFFF000u;

    {
        const int m = s * CAND_ + threadIdx.x;   // CAND_ == 256 == blockDim.x
        const float a0 = xb[m * 3 + 0];
        const float a1 = xb[m * 3 + 1];
        const float a2 = xb[m * 3 + 2];
        sc[threadIdx.x] = make_float4(a0, a1, a2, 0.5f * (a0 * a0 + a1 * a1 + a2 * a2));
    }
    __syncthreads();

    u32 L[16];
#pragma unroll
    for (int i = 0; i < 16; ++i) L[i] = 0xFFFFFFFFu;

    const u32 ibase = (u32)(s * CAND_);
    for (int m0 = 0; m0 < CAND_; m0 += 16) {
        float4 cc[16];
#pragma unroll
        for (int t = 0; t < 16; ++t) cc[t] = sc[m0 + t];
        u32 c[16];
#pragma unroll
        for (int t = 0; t < 16; ++t) {
            const float e = fmaf(nx0, cc[t].x,
                            fmaf(nx1, cc[t].y,
                            fmaf(nx2, cc[t].z, cc[t].w + hs)));
            c[t] = (__float_as_uint(fmaxf(e, 0.0f)) & kmask) | (ibase + (u32)(m0 + t));
        }
        sort16_desc(c);
#pragma unroll
        for (int i = 0; i < 16; ++i) L[i] = min(L[i], c[i]);
        remerge16_asc(L);
    }

    const int p = b * N_ + n;
#pragma unroll
    for (int j = 0; j < 16; ++j)
        part[(size_t)(s * 16 + j) * NPTS + p] = L[j];
}

// ---------------- prep body: weight transpose-casts + straight casts (f16) ----------------
static __device__ void prep_body(float (*t)[33],
    const float* __restrict__ wq, const float* __restrict__ wk, const float* __restrict__ wv,
    const float* __restrict__ fd2, const float* __restrict__ fc1, const float* __restrict__ fc2,
    const float* __restrict__ feat,
    f16* __restrict__ catW, f16* __restrict__ fc2T, f16* __restrict__ bt2,
    f16* __restrict__ fd2c, f16* __restrict__ wqc, f16* __restrict__ fc1c,
    f16* __restrict__ featb, int bx, int by, int job)
{
    const int tid = threadIdx.x;

    if (job < 4) {
        const float* in; int R, C;
        switch (job) {
            case 0: in = wq;  R = DM_; C = DM_; break;
            case 1: in = wk;  R = DM_; C = DM_; break;
            case 2: in = wv;  R = DM_; C = DM_; break;
            default: in = fc2; R = DM_; C = DP_; break;
        }
        const int c0 = bx * 32, r0 = by * 32;
        if (c0 >= C || r0 >= R) return;
        const int lx = tid & 31, ly = tid >> 5;
#pragma unroll
        for (int i = 0; i < 32; i += 8)
            t[ly + i][lx] = in[(size_t)(r0 + ly + i) * C + c0 + lx];
        __syncthreads();
#pragma unroll
        for (int i = 0; i < 32; i += 8) {
            const int c = c0 + ly + i;
            const f16 v = (f16)t[lx][ly + i];
            int n;
            switch (job) {
                case 0: n = c; break;
                case 1: n = 256 + ((c >> 2) << 3) + (c & 3); break;
                case 2: n = 256 + ((c >> 2) << 3) + 4 + (c & 3); break;
                default: n = -1; break;
            }
            if (job < 3) {
                catW[(size_t)n * DM_ + r0 + lx] = v;
            } else {
                fc2T[(size_t)c * DM_ + r0 + lx] = v;
                bt2[(size_t)c * 512 + 256 + r0 + lx] = v;
            }
        }
    } else {
        const int bid = by * 8 + bx;                      // 0..63
        const int tId = bid * 256 + tid;
        const float* in; f16* outp; int n4;
        if (job == 4)      { in = fd2;  outp = fd2c;  n4 = (DM_ * DM_) / 4; }
        else if (job == 5) { in = wq;   outp = wqc;   n4 = (DM_ * DM_) / 4; }
        else if (job == 6) { in = fc1;  outp = fc1c;  n4 = (DP_ * DM_) / 4; }
        else               { in = feat; outp = featb; n4 = (NPTS * DP_) / 4; }
        for (int i = tId; i < n4; i += 16384) {
            const float4 v = ((const float4*)in)[i];
            const u32 lo = asu32(pkrtz(v.x, v.y));
            const u32 hi = asu32(pkrtz(v.z, v.w));
            ((uint2*)outp)[i] = make_uint2(lo, hi);
        }
    }
}

// ---------------- FUSED prep (512 blocks) + knn_part (1024 blocks) ----------------
__global__ __launch_bounds__(256) void fused_prep_knn_kernel(
    const float* __restrict__ wq, const float* __restrict__ wk, const float* __restrict__ wv,
    const float* __restrict__ fd2, const float* __restrict__ fc1, const float* __restrict__ fc2,
    const float* __restrict__ feat,
    f16* __restrict__ catW, f16* __restrict__ fc2T, f16* __restrict__ bt2,
    f16* __restrict__ fd2c, f16* __restrict__ wqc, f16* __restrict__ fc1c,
    f16* __restrict__ featb,
    const float* __restrict__ xyz, u32* __restrict__ part)
{
    __shared__ __align__(16) char smem[4352];
    const int id = blockIdx.x;
    if (id < 512) {
        prep_body((float(*)[33])smem, wq, wk, wv, fd2, fc1, fc2, feat,
                  catW, fc2T, bt2, fd2c, wqc, fc1c, featb,
                  id & 7, (id >> 3) & 7, id >> 6);
    } else {
        knn_part_body((float4*)smem, xyz, part, id - 512);
    }
}

// ---------------- generic BK=32 GEMM tile (C[M,N] = A@Bt^T, f16 out) ----------------
static __device__ void gemm_tile(f16* As, f16* Bs,
    const f16* __restrict__ A, const f16* __restrict__ Bt,
    f16* __restrict__ Cb,
    int M, int N, int K, int ldc, int bx, int by)
{
    const int tid = threadIdx.x;
    const int m0 = by * 128, n0 = bx * 128;
    const int w = tid >> 6, l = tid & 63;
    const int wm = (w >> 1) * 64, wn = (w & 1) * 64;
    const int fm = l & 15, kq = l >> 4;

    floatx4 acc[4][4];
#pragma unroll
    for (int i = 0; i < 4; ++i)
#pragma unroll
        for (int j = 0; j < 4; ++j)
            acc[i][j] = (floatx4){0.0f, 0.0f, 0.0f, 0.0f};

    for (int k0 = 0; k0 < K; k0 += 32) {
        __syncthreads();
#pragma unroll
        for (int c = 0; c < 2; ++c) {
            const int li = tid + c * 256;
            const int row = li >> 2, part = li & 3;
            *(uint4*)&As[row * 32 + part * 8] =
                *(const uint4*)&A[(size_t)(m0 + row) * K + k0 + part * 8];
            *(uint4*)&Bs[row * 32 + part * 8] =
                *(const uint4*)&Bt[(size_t)(n0 + row) * K + k0 + part * 8];
        }
        __syncthreads();
        f16x8 af[4], bf[4];
#pragma unroll
        for (int i = 0; i < 4; ++i)
            af[i] = *(const f16x8*)&As[(wm + i * 16 + fm) * 32 + kq * 8];
#pragma unroll
        for (int j = 0; j < 4; ++j)
            bf[j] = *(const f16x8*)&Bs[(wn + j * 16 + fm) * 32 + kq * 8];
#pragma unroll
        for (int i = 0; i < 4; ++i)
#pragma unroll
            for (int j = 0; j < 4; ++j)
                acc[i][j] = __builtin_amdgcn_mfma_f32_16x16x32_f16(af[i], bf[j], acc[i][j], 0, 0, 0);
    }

#pragma unroll
    for (int i = 0; i < 4; ++i) {
#pragma unroll
        for (int j = 0; j < 4; ++j) {
            const int col = n0 + wn + j * 16 + fm;
            const int rowb = m0 + wm + i * 16 + kq * 4;
#pragma unroll
            for (int r = 0; r < 4; ++r)
                Cb[(size_t)(rowb + r) * ldc + col] = (f16)acc[i][j][r];
        }
    }
}

static __device__ void mergeAB_body(const u32* __restrict__ part, int* __restrict__ knn_idx,
                                    int id)
{
    const int p = id * 256 + threadIdx.x;
    const int b = p >> 12;

    u32 L[16];
#pragma unroll
    for (int i = 0; i < 16; ++i) L[i] = 0xFFFFFFFFu;

    for (int s = 0; s < SEG_; ++s) {
        u32 seg[16];
#pragma unroll
        for (int j = 0; j < 16; ++j)
            seg[j] = part[(size_t)(s * 16 + j) * NPTS + p];
#pragma unroll
        for (int i = 0; i < 16; ++i) L[i] = min(L[i], seg[15 - i]);
        remerge16_asc(L);
    }

    int* o = knn_idx + (size_t)p * K_;
#pragma unroll
    for (int i = 0; i < 16; ++i) o[i] = b * N_ + (int)(L[i] & 0xFFFu);
}

// ---------------- qkv GEMM, 32-row x 1024-col blocks, per-tile kvw/ubuf pack ----------
// Block computes all 1024 output cols for 32 rows (B streamed through LDS).
// kv n-tiles (cols 256..767, 16 groups per 128-col tile) are staged per-tile in
// a small LDS buffer then packed directly to fp8 kvw rows + w/u vectors -- the
// kv cols never touch HBM as f16. LDS total 52 KB -> 2 blocks/CU at grid 512.
// Blocks 512.. run the 16-segment KNN merge (fused to save a launch).
__global__ __launch_bounds__(256) void gemm_qkv_fused_kernel(
    const f16* __restrict__ A,     // featb [NPTS][128]
    const f16* __restrict__ Bt,    // WallT [1024][128]
    const float* __restrict__ bias,
    const float* __restrict__ xyz,
    const float* __restrict__ fd1_w, const float* __restrict__ fd1_b,
    f16* __restrict__ Cb,          // qkv [NPTS][1024] (q/qp cols only)
    u8* __restrict__ kvw, f16* __restrict__ ubuf,
    const u32* __restrict__ part, int* __restrict__ knn_idx)
{
    __shared__ __align__(16) f16 As[32 * 136];
    __shared__ __align__(16) f16 Bs[128 * 136];
    __shared__ __align__(16) f16 kvstage[32 * 136];
    const int bid = blockIdx.x;
    if (bid >= 512) { mergeAB_body(part, knn_idx, bid - 512); return; }

    const int tid = threadIdx.x;
    const int m0 = bid * 32;
    const int w = tid >> 6, l = tid & 63;
    const int wr = (w >> 1) * 16;          // wave row offset within 32
    const int wn = (w & 1) * 64;           // wave col offset within 128-tile
    const int fm = l & 15, kq = l >> 4;

    // stage A rows m0..m0+31: 32 rows x 16 uint4-chunks = 512 slots
#pragma unroll
    for (int c = 0; c < 2; ++c) {
        const int li = tid + c * 256;      // 0..511
        const int row = li >> 4, pt = li & 15;
        *(uint4*)&As[row * 136 + pt * 8] =
            *(const uint4*)&A[(size_t)(m0 + row) * 128 + pt * 8];
    }

    for (int nt = 0; nt < 8; ++nt) {
        __syncthreads();   // As ready (iter 0) / prior Bs + kvstage reads done
        // stage B rows nt*128..+127: 128 rows x 16 chunks = 2048 slots
#pragma unroll
        for (int c = 0; c < 8; ++c) {
            const int li = tid + c * 256;  // 0..2047
            const int row = li >> 4, pt = li & 15;
            *(uint4*)&Bs[row * 136 + pt * 8] =
                *(const uint4*)&Bt[(size_t)(nt * 128 + row) * 128 + pt * 8];
        }
        __syncthreads();

        floatx4 acc[4];
#pragma unroll
        for (int j = 0; j < 4; ++j)
            acc[j] = (floatx4){0.0f, 0.0f, 0.0f, 0.0f};

#pragma unroll
        for (int kk = 0; kk < 4; ++kk) {
            f16x8 af, bf[4];
            af = *(const f16x8*)&As[(wr + fm) * 136 + kk * 32 + kq * 8];
#pragma unroll
            for (int j = 0; j < 4; ++j)
                bf[j] = *(const f16x8*)&Bs[(wn + j * 16 + fm) * 136 + kk * 32 + kq * 8];
#pragma unroll
            for (int j = 0; j < 4; ++j)
                acc[j] = __builtin_amdgcn_mfma_f32_16x16x32_f16(af, bf[j], acc[j], 0, 0, 0);
        }

        if (nt >= 2 && nt < 6) {
            // kv tile: stage f16 (identical rounding to the old global
            // round-trip), then pack this tile's 16 groups to kvw + ubuf.
#pragma unroll
            for (int j = 0; j < 4; ++j) {
                const int col = nt * 128 + wn + j * 16 + fm;
                const int lcol = col - nt * 128;           // 0..127
                const int rowb = wr + kq * 4;
#pragma unroll
                for (int r = 0; r < 4; ++r)
                    kvstage[(rowb + r) * 136 + lcol] = (f16)(acc[j][r] + bias[col]);
            }
            __syncthreads();   // kvstage complete

            // pack: 32 rows x 16 groups = 512 tasks, 2 per thread
#pragma unroll
            for (int it = 0; it < 2; ++it) {
                const int task = it * 256 + tid;
                const int pl = task >> 4, gl = task & 15;
                const int p = m0 + pl;
                const int g = (nt - 2) * 16 + gl;          // global group 0..63
                const uint4 kv = *(const uint4*)&kvstage[pl * 136 + gl * 8];
                const h2 k01 = ash2(kv.x), k23 = ash2(kv.y);
                const h2 v01 = ash2(kv.z), v23 = ash2(kv.w);
                int lo = 0, hi = 0;
                lo = __builtin_amdgcn_cvt_pk_fp8_f32((float)k01.x, (float)k01.y, lo, false);
                lo = __builtin_amdgcn_cvt_pk_fp8_f32((float)k23.x, (float)k23.y, lo, true);
                hi = __builtin_amdgcn_cvt_pk_fp8_f32((float)v01.x, (float)v01.y, hi, false);
                hi = __builtin_amdgcn_cvt_pk_fp8_f32((float)v23.x, (float)v23.y, hi, true);

                const float x0 = xyz[(size_t)p * 3 + 0];
                const float x1 = xyz[(size_t)p * 3 + 1];
                const float x2 = xyz[(size_t)p * 3 + 2];
                const int c0 = g * 4;
                const float4 w0v = *(const float4*)&fd1_w[c0];
                const float4 w1v = *(const float4*)&fd1_w[DM_ + c0];
                const float4 w2v = *(const float4*)&fd1_w[2 * DM_ + c0];
                const float4 b1v = *(const float4*)&fd1_b[c0];
                const float ww0 = x0 * w0v.x + x1 * w1v.x + x2 * w2v.x;
                const float ww1 = x0 * w0v.y + x1 * w1v.y + x2 * w2v.y;
                const float ww2 = x0 * w0v.z + x1 * w1v.z + x2 * w2v.z;
                const float ww3 = x0 * w0v.w + x1 * w1v.w + x2 * w2v.w;

                uint4 row;
                row.x = (u32)lo;
                row.y = (u32)hi;
                row.z = asu32(pkrtz(ww0, ww1));
                row.w = asu32(pkrtz(ww2, ww3));
                *(uint4*)(kvw + (size_t)p * 1024 + g * 16) = row;

                const uint2 uu = make_uint2(asu32(pkrtz(ww0 + b1v.x, ww1 + b1v.y)),
                                            asu32(pkrtz(ww2 + b1v.z, ww3 + b1v.w)));
                *(uint2*)(ubuf + (size_t)p * 256 + c0) = uu;
            }
        } else {
            // q / qp tile: write to qkv as before
#pragma unroll
            for (int j = 0; j < 4; ++j) {
                const int col = nt * 128 + wn + j * 16 + fm;
                const int rowb = m0 + wr + kq * 4;
#pragma unroll
                for (int r = 0; r < 4; ++r)
                    Cb[(size_t)(rowb + r) * 1024 + col] = (f16)(acc[j][r] + bias[col]);
            }
        }
    }
}

// ---------------- out GEMM: 64x128 tile (256 blocks — full CU coverage) ----------------
__global__ __launch_bounds__(256) void gemm_out_kernel(
    const f16* __restrict__ A,      // ab [NPTS][512]
    const f16* __restrict__ Bt,     // bt2 [128][512]
    const float* __restrict__ bias2,
    const float* __restrict__ feat, // [NPTS][128] fp32
    float* __restrict__ CT)         // [B][DP][N]
{
    __shared__ __align__(16) f16 As[64 * 32];
    __shared__ __align__(16) f16 Bs[128 * 32];
    const int tid = threadIdx.x;
    const int m0 = blockIdx.x * 64;
    const int w = tid >> 6, l = tid & 63;
    const int wn = w * 32;
    const int fm = l & 15, kq = l >> 4;

    floatx4 acc[4][2];
#pragma unroll
    for (int i = 0; i < 4; ++i)
#pragma unroll
        for (int j = 0; j < 2; ++j)
            acc[i][j] = (floatx4){0.0f, 0.0f, 0.0f, 0.0f};

    for (int k0 = 0; k0 < 512; k0 += 32) {
        __syncthreads();
        {
            const int row = tid >> 2, part = tid & 3;
            *(uint4*)&As[row * 32 + part * 8] =
                *(const uint4*)&A[(size_t)(m0 + row) * 512 + k0 + part * 8];
        }
#pragma unroll
        for (int c = 0; c < 2; ++c) {
            const int li = tid + c * 256;
            const int row = li >> 2, part = li & 3;
            *(uint4*)&Bs[row * 32 + part * 8] =
                *(const uint4*)&Bt[(size_t)row * 512 + k0 + part * 8];
        }
        __syncthreads();
        f16x8 af[4], bf[2];
#pragma unroll
        for (int i = 0; i < 4; ++i)
            af[i] = *(const f16x8*)&As[(i * 16 + fm) * 32 + kq * 8];
#pragma unroll
        for (int j = 0; j < 2; ++j)
            bf[j] = *(const f16x8*)&Bs[(wn + j * 16 + fm) * 32 + kq * 8];
#pragma unroll
        for (int i = 0; i < 4; ++i)
#pragma unroll
            for (int j = 0; j < 2; ++j)
                acc[i][j] = __builtin_amdgcn_mfma_f32_16x16x32_f16(af[i], bf[j], acc[i][j], 0, 0, 0);
    }

#pragma unroll
    for (int i = 0; i < 4; ++i) {
#pragma unroll
        for (int j = 0; j < 2; ++j) {
            const int col = wn + j * 16 + fm;
            const int rowb = m0 + i * 16 + kq * 4;
            float4 vv;
#pragma unroll
            for (int r = 0; r < 4; ++r)
                ((float*)&vv)[r] = acc[i][j][r] + bias2[col]
                                 + feat[(size_t)(rowb + r) * DP_ + col];
            const int bb = rowb >> 12;
            *(float4*)&CT[(size_t)(bb * DP_ + col) * N_ + (rowb & (N_ - 1))] = vv;
        }
    }
}

// ---------------- fused small GEMMs 1: wqp (4 tiles) + bt2 (2 tiles) ----------------
__global__ __launch_bounds__(256) void fused_small1_kernel(
    const f16* __restrict__ fd2c, const f16* __restrict__ wqc,
    f16* __restrict__ catWqp,
    const f16* __restrict__ fc2T, f16* __restrict__ bt2)
{
    __shared__ __align__(16) f16 As[128 * 32];
    __shared__ __align__(16) f16 Bs[128 * 32];
    const int id = blockIdx.x;
    if (id < 4)
        gemm_tile(As, Bs, fd2c, wqc, catWqp, DM_, DM_, DM_, DM_, id & 1, id >> 1);
    else
        gemm_tile(As, Bs, fc2T, fd2c, bt2, DP_, DM_, DM_, 512, id - 4, 0);
}

// ---------------- fused small GEMMs 2: WallT (8 tiles) + folded biases (5 blocks) ----------------
__global__ __launch_bounds__(256) void fused_small2_kernel(
    const f16* __restrict__ catW, const f16* __restrict__ fc1c, f16* __restrict__ WallT,
    const float* __restrict__ fc1_b, const float* __restrict__ fd2_b,
    const float* __restrict__ fc2_w, const float* __restrict__ fc2_b,
    float* __restrict__ b_all, float* __restrict__ bias2)
{
    __shared__ __align__(16) f16 As[128 * 32];
    __shared__ __align__(16) f16 Bs[128 * 32];
    const int id = blockIdx.x;
    const int tid = threadIdx.x;
    if (id < 8) {
        gemm_tile(As, Bs, catW, fc1c, WallT, 1024, DP_, DM_, DP_, 0, id);
    } else if (id < 12) {
        const int n = (id - 8) * 256 + tid;
        float s = 0.0f;
        for (int j = 0; j < DM_; ++j)
            s += fc1_b[j] * (float)catW[(size_t)n * DM_ + j];
        b_all[n] = s;
    } else if (tid < DP_) {
        float s = fc2_b[tid];
        for (int t = 0; t < DM_; ++t)
            s += fd2_b[t] * fc2_w[(size_t)t * DP_ + tid];
        bias2[tid] = s;
    }
}

// ---------------- fused attention: 2x8-row batched prefetch, single-touch rows ------
// Round-6 counters showed VGPR_Count=56 < the 64 needed to hold a 16-row uint4
// prefetch -> the compiler was re-issuing gathers inside the compute (latency-
// serialized). Restructure: two batches of 8 independent 16B loads; each row is
// consumed ONCE in phase 1 (h kept as packed u32, v kept as raw u32 word) so
// nothing forces a reload. Float ops / order identical -> bit-identical output.
__global__ __launch_bounds__(256) void attn_kernel(
    const f16* __restrict__ qkv, const u8* __restrict__ kvw,
    const f16* __restrict__ ubuf, const int* __restrict__ knn_idx,
    const float* __restrict__ fd2_b,
    f16* __restrict__ ab)
{
    const int wave = threadIdx.x >> 6, l = threadIdx.x & 63;
    const int bi = blockIdx.x;
    const int p = ((bi & 3) << 12) + ((bi >> 2) << 2) + wave;   // batch-pinned remap
    const int c0 = l * 4;

    int gi = 0;
    if (l < 16) gi = knn_idx[p * K_ + l];

    const uint2 qu  = *(const uint2*)(qkv + (size_t)p * 1024 + c0);
    const uint2 qpu = *(const uint2*)(qkv + (size_t)p * 1024 + 768 + c0);
    const uint2 uu  = *(const uint2*)(ubuf + (size_t)p * 256 + c0);
    const h2 qh01 = ash2(qu.x), qh23 = ash2(qu.y);
    const h2 qp01 = ash2(qpu.x), qp23 = ash2(qpu.y);
    const h2 u01 = ash2(uu.x), u23 = ash2(uu.y);
    const float q0 = (float)qh01.x, q1 = (float)qh01.y, q2 = (float)qh23.x, q3 = (float)qh23.y;
    const h2 zero2 = (h2)(__fp16)0.0f;

    const float4 f2b = *(const float4*)&fd2_b[c0];

    // qb = q . fd2_b (constant over k)
    float qb;
    {
        float tq = q0 * f2b.x + q1 * f2b.y + q2 * f2b.z + q3 * f2b.w;
#pragma unroll
        for (int off = 1; off < 64; off <<= 1) tq += __shfl_xor(tq, off);
        qb = tq;
    }

    // phase 1 in two batches of 8: issue 8 independent 16B gathers, then consume
    // each row fully. Keep only h (2 u32/k) and the raw v word (1 u32/k).
    float lg[16];
    u32 h01r[16], h23r[16], vyr[16];
#pragma unroll
    for (int half = 0; half < 2; ++half) {
        uint4 r8[8];
#pragma unroll
        for (int k = 0; k < 8; ++k) {
            const int gik = __shfl(gi, half * 8 + k);
            r8[k] = *(const uint4*)(kvw + (size_t)gik * 1024 + l * 16);
        }
#pragma unroll
        for (int k = 0; k < 8; ++k) {
            const int kk = half * 8 + k;
            const uint4 r = r8[k];
            h2 d01 = u01 - ash2(r.z);
            h2 d23 = u23 - ash2(r.w);
            d01 = __builtin_elementwise_max(d01, zero2);
            d23 = __builtin_elementwise_max(d23, zero2);
            h01r[kk] = asu32(d01); h23r[kk] = asu32(d23);
            vyr[kk] = r.y;
            const auto k01 = __builtin_amdgcn_cvt_pk_f32_fp8((int)r.x, false);
            const auto k23 = __builtin_amdgcn_cvt_pk_f32_fp8((int)r.x, true);
            float t = q0 * k01[0] + q1 * k01[1] + q2 * k23[0] + q3 * k23[1];
            t = __builtin_amdgcn_fdot2(d01, qp01, t, false);
            t = __builtin_amdgcn_fdot2(d23, qp23, t, false);
#pragma unroll
            for (int off = 1; off < 64; off <<= 1) t += __shfl_xor(t, off);
            lg[kk] = t;
        }
    }

    // softmax over 16 (redundant per lane, all registers)
    float att[16];
    {
        float mx = -3.0e38f;
#pragma unroll
        for (int k = 0; k < 16; ++k) {
            att[k] = (lg[k] + qb) * (1.0f / 16.0f);
            mx = fmaxf(mx, att[k]);
        }
        float s = 0.0f;
#pragma unroll
        for (int k = 0; k < 16; ++k) { att[k] = __expf(att[k] - mx); s += att[k]; }
        const float inv = 1.0f / s;
#pragma unroll
        for (int k = 0; k < 16; ++k) att[k] *= inv;
    }

    // phase 2: pure VALU — rbar = sum att*v (vyr regs), hbar = sum att*h (regs)
    float rb[4] = {0, 0, 0, 0}, hb[4] = {0, 0, 0, 0};
#pragma unroll
    for (int k = 0; k < 16; ++k) {
        const auto v01 = __builtin_amdgcn_cvt_pk_f32_fp8((int)vyr[k], false);
        const auto v23 = __builtin_amdgcn_cvt_pk_f32_fp8((int)vyr[k], true);
        const h2 hh01 = ash2(h01r[k]), hh23 = ash2(h23r[k]);
        const float a = att[k];
        rb[0] = fmaf(a, v01[0], rb[0]);
        rb[1] = fmaf(a, v01[1], rb[1]);
        rb[2] = fmaf(a, v23[0], rb[2]);
        rb[3] = fmaf(a, v23[1], rb[3]);
        hb[0] = fmaf(a, (float)hh01.x, hb[0]);
        hb[1] = fmaf(a, (float)hh01.y, hb[1]);
        hb[2] = fmaf(a, (float)hh23.x, hb[2]);
        hb[3] = fmaf(a, (float)hh23.y, hb[3]);
    }

    const uint2 ho = make_uint2(asu32(pkrtz(hb[0], hb[1])), asu32(pkrtz(hb[2], hb[3])));
    const uint2 ro = make_uint2(asu32(pkrtz(rb[0], rb[1])), asu32(pkrtz(rb[2], rb[3])));
    *(uint2*)(ab + (size_t)p * 512 + c0) = ho;
    *(uint2*)(ab + (size_t)p * 512 + 256 + c0) = ro;
}

extern "C" void kernel_launch(void* const* d_in, const int* in_sizes, int n_in,
                              void* d_out, int out_size, void* d_ws, size_t ws_size,
                              hipStream_t stream)
{
    const float* features = (const float*)d_in[0];
    const float* xyz   = (const float*)d_in[1];
    const float* fc1_w = (const float*)d_in[2];
    const float* fc1_b = (const float*)d_in[3];
    const float* fc2_w = (const float*)d_in[4];
    const float* fc2_b = (const float*)d_in[5];
    const float* fd1_w = (const float*)d_in[6];
    const float* fd1_b = (const float*)d_in[7];
    const float* fd2_w = (const float*)d_in[8];
    const float* fd2_b = (const float*)d_in[9];
    const float* wq    = (const float*)d_in[10];
    const float* wk    = (const float*)d_in[11];
    const float* wv    = (const float*)d_in[12];
    float* out = (float*)d_out;

    char* base = (char*)d_ws;
    const size_t MB = 1024 * 1024;
    u32*  part = (u32*)(base + 0);                 // 16 MB (16 segs), dead after merge
    f16*  ab   = (f16*)(base + 0);                 // 16 MB [hbar|rbar]
    u8*   kvw  = (u8*)(base + 20 * MB);            // 16 MB {k fp8, v fp8, w f16} rows
    f16*  qkv  = (f16*)(base + 36 * MB);           // 32 MB (q/qp cols live)
    f16*  featb = (f16*)(base + 68 * MB);          // 4 MB
    int*  idx  = (int*)(base + 72 * MB);           // 1 MB
    char* wb = base + 73 * MB;
    f16* catW  = (f16*)(wb + 0);                   // 512 KB
    f16* WallT = (f16*)(wb + 512 * 1024);          // 256 KB
    f16* bt2   = (f16*)(wb + 768 * 1024);          // 128 KB
    f16* fd2c  = (f16*)(wb + 896 * 1024);
    f16* wqc   = (f16*)(wb + 1024 * 1024);
    f16* fc1c  = (f16*)(wb + 1152 * 1024);
    f16* fc2T  = (f16*)(wb + 1216 * 1024);
    float* b_all = (float*)(wb + 1280 * 1024);
    float* bias2 = (float*)(wb + 1284 * 1024);
    f16*  ubuf = (f16*)(base + 76 * MB);           // 8 MB u = xyz.fd1 + b (f16)

    const dim3 blk(256);

    // 1. prep casts (512 blocks) || KNN partial top-16 (1024 blocks)
    fused_prep_knn_kernel<<<dim3(512 + 1024), blk, 0, stream>>>(
        wq, wk, wv, fd2_w, fc1_w, fc2_w, features,
        catW, fc2T, bt2, fd2c, wqc, fc1c, featb, xyz, part);
    // 2. wqp -> catW rows 768.. (4 tiles) || bt2 cols [0,256) (2 tiles)
    fused_small1_kernel<<<dim3(6), blk, 0, stream>>>(fd2c, wqc, catW + 768 * 256, fc2T, bt2);
    // 3. WallT (8 tiles) || b_all (4) || bias2 (1)
    fused_small2_kernel<<<dim3(13), blk, 0, stream>>>(catW, fc1c, WallT,
                                                      fc1_b, fd2_b, fc2_w, fc2_b, b_all, bias2);
    // 4. qkv GEMM BM=32 (kv -> per-tile fp8 pack in LDS) || KNN merge (64 blocks)
    gemm_qkv_fused_kernel<<<dim3(512 + 64), blk, 0, stream>>>(
        featb, WallT, b_all, xyz, fd1_w, fd1_b, qkv, kvw, ubuf, part, idx);
    // 5. fused attention -> ab = [hbar | rbar]  (XCD batch-pinned block remap)
    attn_kernel<<<dim3(NPTS / 4), blk, 0, stream>>>(qkv, kvw, ubuf, idx, fd2_b, ab);
    // 6. out GEMM: 64x128 tiles -> 256 blocks, fused transpose + bias + residual
    gemm_out_kernel<<<dim3(NPTS / 64), blk, 0, stream>>>(ab, bt2, bias2, features, out);

    (void)in_sizes; (void)n_in; (void)out_size; (void)ws_size;
}